// Round 1
// baseline (590.798 us; speedup 1.0000x reference)
//
#include <hip/hip_runtime.h>
#include <hip/hip_bf16.h>
#include <stdint.h>
#include <stddef.h>

typedef __hip_bfloat16 bf16;
typedef short bf16x8s __attribute__((ext_vector_type(8)));
typedef float f32x4 __attribute__((ext_vector_type(4)));
typedef int i32x4 __attribute__((ext_vector_type(4)));
typedef unsigned long long u64;

#define NPROP 1000
#define MPAD  1024
#define NCG   80        // foreground classes
#define NCLS  81        // incl background
#define CH    256
#define KDIM  12544     // 256*49
#define CLIN  1024
#define IMGSZ 800.0f
#define SCORE_THR 0.05f
#define MIN_SIZE 0.01f
#define KNMS 1000
#define CAND 4096
#define SPLITK 4
#define DWH_CLAMP_F 4.135166556742356f

// ---------------- feature map transpose: NCHW f32 -> NHWC bf16 ----------------
__global__ void fm_transpose(const float* __restrict__ fm, bf16* __restrict__ fmt, int S) {
    __shared__ float tile[32][33];
    int b = blockIdx.z;
    int sBase = blockIdx.x * 32;
    int cBase = blockIdx.y * 32;
    int tx = threadIdx.x, ty = threadIdx.y;
#pragma unroll
    for (int i = 0; i < 4; ++i) {
        int c = cBase + ty + i * 8;
        int s = sBase + tx;
        float v = 0.f;
        if (s < S) v = fm[((size_t)(b * CH + c)) * S + s];
        tile[ty + i * 8][tx] = v;
    }
    __syncthreads();
#pragma unroll
    for (int i = 0; i < 4; ++i) {
        int s = sBase + ty + i * 8;
        int c = cBase + tx;
        if (s < S) fmt[((size_t)b * S + s) * CH + c] = __float2bfloat16(tile[tx][ty + i * 8]);
    }
}

// --------- W_fc0 (12544x1024) -> Wt0 (1024 x 12544) with k' = cell*256 + c ----------
__global__ void wfc0_transpose(const float* __restrict__ W, bf16* __restrict__ Wt) {
    __shared__ float tile[32][33];
    int cell = blockIdx.x;          // 0..48
    int cBase = blockIdx.y * 32;    // channel block
    int nBase = blockIdx.z * 32;    // output-neuron block
    int tx = threadIdx.x, ty = threadIdx.y;
#pragma unroll
    for (int i = 0; i < 4; ++i) {
        int c = cBase + ty + i * 8;
        int k = c * 49 + cell;
        tile[ty + i * 8][tx] = W[(size_t)k * CLIN + nBase + tx];
    }
    __syncthreads();
#pragma unroll
    for (int i = 0; i < 4; ++i) {
        int n = nBase + ty + i * 8;
        Wt[(size_t)n * KDIM + cell * CH + cBase + tx] = __float2bfloat16(tile[tx][ty + i * 8]);
    }
}

// --------- generic W (1024 x ncols) -> Wt (npad x 1024) bf16, zero pad rows ----------
__global__ void w_transpose(const float* __restrict__ W, bf16* __restrict__ Wt, int ncols) {
    __shared__ float tile[32][33];
    int kBase = blockIdx.x * 32;
    int nBase = blockIdx.y * 32;
    int tx = threadIdx.x, ty = threadIdx.y;
#pragma unroll
    for (int i = 0; i < 4; ++i) {
        int k = kBase + ty + i * 8;
        int n = nBase + tx;
        float v = 0.f;
        if (n < ncols) v = W[(size_t)k * ncols + n];
        tile[ty + i * 8][tx] = v;
    }
    __syncthreads();
#pragma unroll
    for (int i = 0; i < 4; ++i) {
        int n = nBase + ty + i * 8;
        Wt[(size_t)n * CLIN + kBase + tx] = __float2bfloat16(tile[tx][ty + i * 8]);
    }
}

// ---------------- RoI align: one block per proposal, thread = channel ----------------
__global__ __launch_bounds__(256) void roi_align(
    const float* __restrict__ props, const int* __restrict__ imidx,
    const bf16* __restrict__ f0, const bf16* __restrict__ f1,
    const bf16* __restrict__ f2, const bf16* __restrict__ f3,
    bf16* __restrict__ x0) {
    int n = blockIdx.x;
    int c = threadIdx.x;
    if (n >= NPROP) {   // zero pad rows (deterministic GEMM input)
        for (int cell = 0; cell < 49; ++cell)
            x0[(size_t)n * KDIM + cell * CH + c] = __float2bfloat16(0.f);
        return;
    }
    float px1 = props[n * 4 + 0], py1 = props[n * 4 + 1];
    float px2 = props[n * 4 + 2], py2 = props[n * 4 + 3];
    float w = px2 - px1, h = py2 - py1;
    float lvlf = floorf(4.0f + log2f(sqrtf(fmaxf(w * h, 1e-6f)) / 224.0f));
    int lvl = (int)fminf(fmaxf(lvlf, 2.0f), 5.0f) - 2;
    const bf16* fmt; int H, Wd; float stride;
    if (lvl == 0)      { fmt = f0; H = 200; Wd = 200; stride = 4.f; }
    else if (lvl == 1) { fmt = f1; H = 100; Wd = 100; stride = 8.f; }
    else if (lvl == 2) { fmt = f2; H = 50;  Wd = 50;  stride = 16.f; }
    else               { fmt = f3; H = 25;  Wd = 25;  stride = 32.f; }
    int b = imidx[n];
    const bf16* base = fmt + (size_t)b * H * Wd * CH;
    float inv = 1.0f / stride;
    float x1s = px1 * inv, x2s = px2 * inv, y1s = py1 * inv, y2s = py2 * inv;
    for (int i = 0; i < 7; ++i) {
        for (int j = 0; j < 7; ++j) {
            float acc = 0.f;
#pragma unroll
            for (int sy = 0; sy < 2; ++sy) {
#pragma unroll
                for (int sx = 0; sx < 2; ++sx) {
                    float fy = ((float)(i * 2 + sy) + 0.5f) * (1.0f / 14.0f);
                    float fx = ((float)(j * 2 + sx) + 0.5f) * (1.0f / 14.0f);
                    float gy = fminf(fmaxf(y1s + fy * (y2s - y1s), 0.f), (float)(H - 1));
                    float gx = fminf(fmaxf(x1s + fx * (x2s - x1s), 0.f), (float)(Wd - 1));
                    float y0f = floorf(gy), x0f = floorf(gx);
                    int y0i = (int)y0f, x0i = (int)x0f;
                    int y1i = min(y0i + 1, H - 1), x1i = min(x0i + 1, Wd - 1);
                    float ly = gy - y0f, lx = gx - x0f;
                    float v00 = __bfloat162float(base[((size_t)y0i * Wd + x0i) * CH + c]);
                    float v01 = __bfloat162float(base[((size_t)y0i * Wd + x1i) * CH + c]);
                    float v10 = __bfloat162float(base[((size_t)y1i * Wd + x0i) * CH + c]);
                    float v11 = __bfloat162float(base[((size_t)y1i * Wd + x1i) * CH + c]);
                    acc += (1.f - ly) * ((1.f - lx) * v00 + lx * v01)
                         + ly * ((1.f - lx) * v10 + lx * v11);
                }
            }
            x0[(size_t)n * KDIM + (i * 7 + j) * CH + c] = __float2bfloat16(acc * 0.25f);
        }
    }
}

// ---------------- bf16 MFMA NT-GEMM: C = A(MPADxK) * B(NpadxK)^T ----------------
#define BM 128
#define BN 128
#define BK 64
__global__ __launch_bounds__(256) void gemm_nt(
    const bf16* __restrict__ A, const bf16* __restrict__ B,
    int K, int kSteps,
    float* __restrict__ outF32, bf16* __restrict__ outBf16,
    const float* __restrict__ bias, int relu,
    int ldc, int nStore, size_t zStride) {
    __shared__ short Al[BM * BK];
    __shared__ short Bl[BN * BK];
    int tid = threadIdx.x;
    int bm = blockIdx.x * BM;
    int bn = blockIdx.y * BN;
    int z = blockIdx.z;
    int k0 = z * kSteps * BK;

    int wave = tid >> 6, lane = tid & 63;
    int wm = (wave >> 1) * 64, wn = (wave & 1) * 64;
    int lr = lane & 15;
    int lk = lane >> 4;

    f32x4 acc[4][4];
    f32x4 zero4 = {0.f, 0.f, 0.f, 0.f};
#pragma unroll
    for (int i = 0; i < 4; ++i)
#pragma unroll
        for (int j = 0; j < 4; ++j) acc[i][j] = zero4;

    for (int kt = 0; kt < kSteps; ++kt) {
        int kb = k0 + kt * BK;
#pragma unroll
        for (int it = 0; it < 4; ++it) {
            int li = tid + it * 256;
            int row = li >> 3, ch = li & 7;
            i32x4 va = *(const i32x4*)(A + (size_t)(bm + row) * K + kb + ch * 8);
            ((i32x4*)Al)[row * 8 + (ch ^ (row & 7))] = va;
            i32x4 vb = *(const i32x4*)(B + (size_t)(bn + row) * K + kb + ch * 8);
            ((i32x4*)Bl)[row * 8 + (ch ^ (row & 7))] = vb;
        }
        __syncthreads();
#pragma unroll
        for (int ks = 0; ks < 2; ++ks) {
            bf16x8s af[4], bfr[4];
#pragma unroll
            for (int i = 0; i < 4; ++i) {
                int row = wm + i * 16 + lr;
                int ch = (ks * 4 + lk) ^ (row & 7);
                af[i] = ((const bf16x8s*)Al)[row * 8 + ch];
            }
#pragma unroll
            for (int j = 0; j < 4; ++j) {
                int row = wn + j * 16 + lr;
                int ch = (ks * 4 + lk) ^ (row & 7);
                bfr[j] = ((const bf16x8s*)Bl)[row * 8 + ch];
            }
#pragma unroll
            for (int i = 0; i < 4; ++i)
#pragma unroll
                for (int j = 0; j < 4; ++j)
                    acc[i][j] = __builtin_amdgcn_mfma_f32_16x16x32_bf16(af[i], bfr[j], acc[i][j], 0, 0, 0);
        }
        __syncthreads();
    }
    // epilogue: D[row=(lane>>4)*4+r][col=lane&15]
    for (int i = 0; i < 4; ++i) {
        int mbase = bm + wm + i * 16 + lk * 4;
        for (int j = 0; j < 4; ++j) {
            int ncol = bn + wn + j * 16 + lr;
            if (ncol >= nStore) continue;
            float bv = bias ? bias[ncol] : 0.f;
#pragma unroll
            for (int r = 0; r < 4; ++r) {
                int mrow = mbase + r;
                float v = acc[i][j][r] + bv;
                if (relu) v = fmaxf(v, 0.f);
                if (outF32) outF32[(size_t)z * zStride + (size_t)mrow * ldc + ncol] = v;
                if (outBf16) outBf16[(size_t)mrow * ldc + ncol] = __float2bfloat16(v);
            }
        }
    }
}

// ---------------- fc0 split-K reduce + bias + relu -> bf16 ----------------
__global__ void fc0_reduce(const float* __restrict__ Cpart, const float* __restrict__ bias,
                           bf16* __restrict__ x1) {
    int idx = blockIdx.x * 256 + threadIdx.x;
    int ncol = idx & (CLIN - 1);
    float v = bias[ncol];
#pragma unroll
    for (int s = 0; s < SPLITK; ++s) v += Cpart[(size_t)s * MPAD * CLIN + idx];
    x1[idx] = __float2bfloat16(fmaxf(v, 0.f));
}

// ---------------- softmax + box decode + key build ----------------
__global__ __launch_bounds__(128) void decode(
    const float* __restrict__ logits, const float* __restrict__ regb,
    const float* __restrict__ props, const int* __restrict__ imidx,
    float* __restrict__ boxes, u64* __restrict__ keys) {
    __shared__ float red[128];
    int n = blockIdx.x, t = threadIdx.x;
    float l = (t < NCLS) ? logits[(size_t)n * NCLS + t] : -1e30f;
    red[t] = l; __syncthreads();
    for (int s = 64; s > 0; s >>= 1) { if (t < s) red[t] = fmaxf(red[t], red[t + s]); __syncthreads(); }
    float mx = red[0]; __syncthreads();
    float e = (t < NCLS) ? expf(l - mx) : 0.f;
    red[t] = e; __syncthreads();
    for (int s = 64; s > 0; s >>= 1) { if (t < s) red[t] += red[t + s]; __syncthreads(); }
    float denom = red[0];
    if (t >= NCG) return;
    float score = e / denom;
    float px1 = props[n * 4 + 0], py1 = props[n * 4 + 1];
    float px2 = props[n * 4 + 2], py2 = props[n * 4 + 3];
    float pw = px2 - px1, ph = py2 - py1;
    float pcx = px1 + 0.5f * pw, pcy = py1 + 0.5f * ph;
    const float* r4 = regb + ((size_t)n * NCG + t) * 4;
    float dx = r4[0] * 0.1f, dy = r4[1] * 0.1f;
    float dw = fminf(r4[2] * 0.2f, DWH_CLAMP_F);
    float dh = fminf(r4[3] * 0.2f, DWH_CLAMP_F);
    float cx = pcx + dx * pw, cy = pcy + dy * ph;
    float bw = pw * expf(dw), bh = ph * expf(dh);
    float x1 = fminf(fmaxf(cx - 0.5f * bw, 0.f), IMGSZ);
    float y1 = fminf(fmaxf(cy - 0.5f * bh, 0.f), IMGSZ);
    float x2 = fminf(fmaxf(cx + 0.5f * bw, 0.f), IMGSZ);
    float y2 = fminf(fmaxf(cy + 0.5f * bh, 0.f), IMGSZ);
    int idx = n * NCG + t;
    float* bo = boxes + (size_t)idx * 4;
    bo[0] = x1; bo[1] = y1; bo[2] = x2; bo[3] = y2;
    bool valid = (score > SCORE_THR) && ((x2 - x1) >= MIN_SIZE) && ((y2 - y1) >= MIN_SIZE);
    u64 key = 0ull;
    if (valid) key = ((u64)__float_as_uint(score) << 17) | (u64)(0x1FFFFu - (unsigned)idx);
    keys[idx] = key;
}

__global__ void compact(const u64* __restrict__ keys, u64* __restrict__ cand, int* __restrict__ cnt) {
    int i = blockIdx.x * 256 + threadIdx.x;
    if (i >= NPROP * NCG) return;
    u64 k = keys[i];
    if (k) { int p = atomicAdd(cnt, 1); if (p < CAND) cand[p] = k; }
}

// ---------------- bitonic descending sort of 4096 keys, one block ----------------
__global__ __launch_bounds__(1024) void sortk(const u64* __restrict__ cand, u64* __restrict__ sorted) {
    __shared__ u64 s[CAND];
    int t = threadIdx.x;
#pragma unroll
    for (int p = 0; p < 4; ++p) s[t + p * 1024] = cand[t + p * 1024];
    __syncthreads();
    for (int k = 2; k <= CAND; k <<= 1) {
        for (int j = k >> 1; j > 0; j >>= 1) {
#pragma unroll
            for (int p = 0; p < 4; ++p) {
                int i = t + p * 1024;
                int l = i ^ j;
                if (l > i) {
                    u64 a = s[i], b = s[l];
                    bool desc = ((i & k) == 0);
                    if (desc ? (a < b) : (a > b)) { s[i] = b; s[l] = a; }
                }
            }
            __syncthreads();
        }
    }
#pragma unroll
    for (int p = 0; p < 4; ++p) sorted[t + p * 1024] = s[t + p * 1024];
}

// ---------------- gather top-1000 attributes ----------------
__global__ void extract(const u64* __restrict__ sorted, const float* __restrict__ boxes,
                        const int* __restrict__ imidx,
                        float* __restrict__ tb, float* __restrict__ toff,
                        float* __restrict__ ts, int* __restrict__ tc, int* __restrict__ ti) {
    int s = blockIdx.x * 256 + threadIdx.x;
    if (s >= KNMS) return;
    u64 key = sorted[s];
    if (key == 0ull) {
        ts[s] = -1.f; tc[s] = -1; ti[s] = -1;
        for (int d = 0; d < 4; ++d) { tb[s * 4 + d] = 0.f; toff[s * 4 + d] = 0.f; }
        return;
    }
    unsigned idx = 0x1FFFFu - (unsigned)(key & 0x1FFFFull);
    float score = __uint_as_float((unsigned)(key >> 17));
    int n = idx / NCG, c = idx - n * NCG;
    int im = imidx[n];
    float off = (float)(im * NCG + c) * 1000.0f;
    for (int d = 0; d < 4; ++d) {
        float v = boxes[(size_t)idx * 4 + d];
        tb[s * 4 + d] = v;
        toff[s * 4 + d] = v + off;
    }
    ts[s] = score; tc[s] = c; ti[s] = im;
}

// ---------------- greedy NMS, single block ----------------
__global__ __launch_bounds__(256) void nms(const float* __restrict__ toff, const float* __restrict__ ts,
                                           int* __restrict__ keep) {
    __shared__ float4 bx[KNMS];
    __shared__ int kp[KNMS];
    __shared__ int Vsh;
    int t = threadIdx.x;
    if (t == 0) Vsh = KNMS;
    __syncthreads();
    for (int s = t; s < KNMS; s += 256) {
        bx[s] = ((const float4*)toff)[s];
        bool ok = ts[s] > 0.f;
        kp[s] = ok ? 1 : 0;
        if (!ok) atomicMin(&Vsh, s);
    }
    __syncthreads();
    int V = Vsh;   // valid entries form a prefix (sorted descending)
    for (int i = 0; i < V; ++i) {
        if (kp[i]) {
            float4 bi = bx[i];
            float ai = (bi.z - bi.x) * (bi.w - bi.y);
            for (int j2 = i + 1 + t; j2 < V; j2 += 256) {
                if (!kp[j2]) continue;
                float4 bj = bx[j2];
                float xx1 = fmaxf(bi.x, bj.x), yy1 = fmaxf(bi.y, bj.y);
                float xx2 = fminf(bi.z, bj.z), yy2 = fminf(bi.w, bj.w);
                float iw = fmaxf(xx2 - xx1, 0.f), ih = fmaxf(yy2 - yy1, 0.f);
                float inter = iw * ih;
                float aj = (bj.z - bj.x) * (bj.w - bj.y);
                float iou = inter / fmaxf(ai + aj - inter, 1e-9f);
                if (iou > 0.5f) kp[j2] = 0;
            }
        }
        __syncthreads();
    }
    for (int s = t; s < KNMS; s += 256) keep[s] = kp[s];
}

// ---------------- per-image top-100 writeout ----------------
__global__ __launch_bounds__(256) void writeout(
    const float* __restrict__ tb, const float* __restrict__ ts,
    const int* __restrict__ tc, const int* __restrict__ ti,
    const int* __restrict__ keep, float* __restrict__ out) {
    __shared__ short flag[KNMS];
    __shared__ int sel[2][100];
    __shared__ int cnts[2];
    int t = threadIdx.x;
    for (int s = t; s < KNMS; s += 256)
        flag[s] = (keep[s] && ts[s] > 0.f) ? (short)(ti[s] + 1) : (short)0;
    __syncthreads();
    if (t == 0) {
        int c0 = 0, c1 = 0;
        for (int s = 0; s < KNMS; ++s) {
            int f = flag[s];
            if (f == 1) { if (c0 < 100) sel[0][c0++] = s; }
            else if (f == 2) { if (c1 < 100) sel[1][c1++] = s; }
        }
        cnts[0] = c0; cnts[1] = c1;
    }
    __syncthreads();
    for (int r = t; r < 200; r += 256) {
        int im = r / 100, q = r - im * 100;
        if (q < cnts[im]) {
            int s = sel[im][q];
            for (int d = 0; d < 4; ++d) out[(im * 100 + q) * 4 + d] = tb[s * 4 + d];
            out[800 + im * 100 + q] = ts[s];
            out[1000 + im * 100 + q] = (float)tc[s];
        } else {
            for (int d = 0; d < 4; ++d) out[(im * 100 + q) * 4 + d] = 0.f;
            out[800 + im * 100 + q] = 0.f;
            out[1000 + im * 100 + q] = -1.0f;
        }
    }
}

// =====================================================================
extern "C" void kernel_launch(void* const* d_in, const int* in_sizes, int n_in,
                              void* d_out, int out_size, void* d_ws, size_t ws_size,
                              hipStream_t stream) {
    (void)in_sizes; (void)n_in; (void)out_size; (void)ws_size;
    const float* props = (const float*)d_in[0];
    const int*   imidx = (const int*)d_in[1];
    const float* fm0 = (const float*)d_in[2];
    const float* fm1 = (const float*)d_in[3];
    const float* fm2 = (const float*)d_in[4];
    const float* fm3 = (const float*)d_in[5];
    const float* Wfc0 = (const float*)d_in[6];
    const float* bfc0 = (const float*)d_in[7];
    const float* Wfc1 = (const float*)d_in[8];
    const float* bfc1 = (const float*)d_in[9];
    const float* Wcls = (const float*)d_in[10];
    const float* bcls = (const float*)d_in[11];
    const float* Wreg = (const float*)d_in[12];
    const float* breg = (const float*)d_in[13];

    char* p = (char*)d_ws;
    auto alloc = [&](size_t bytes) { char* r = p; p += (bytes + 255) & ~(size_t)255; return r; };

    bf16* fmt0 = (bf16*)alloc((size_t)2 * 40000 * CH * 2);
    bf16* fmt1 = (bf16*)alloc((size_t)2 * 10000 * CH * 2);
    bf16* fmt2 = (bf16*)alloc((size_t)2 * 2500 * CH * 2);
    bf16* fmt3 = (bf16*)alloc((size_t)2 * 625 * CH * 2);
    bf16* Wt0 = (bf16*)alloc((size_t)CLIN * KDIM * 2);
    bf16* Wt1 = (bf16*)alloc((size_t)CLIN * CLIN * 2);
    bf16* Wtc = (bf16*)alloc((size_t)128 * CLIN * 2);
    bf16* Wtr = (bf16*)alloc((size_t)384 * CLIN * 2);
    bf16* x0 = (bf16*)alloc((size_t)MPAD * KDIM * 2);
    bf16* x1 = (bf16*)alloc((size_t)MPAD * CLIN * 2);
    bf16* x2 = (bf16*)alloc((size_t)MPAD * CLIN * 2);
    float* logits = (float*)alloc((size_t)MPAD * NCLS * 4);
    float* regb = (float*)alloc((size_t)MPAD * NCG * 4 * 4);
    float* boxes = (float*)alloc((size_t)NPROP * NCG * 4 * 4);
    u64* keys = (u64*)alloc((size_t)NPROP * NCG * 8);
    u64* cand = (u64*)alloc((size_t)CAND * 8);
    u64* sorted = (u64*)alloc((size_t)CAND * 8);
    float* tb = (float*)alloc(KNMS * 4 * 4);
    float* toff = (float*)alloc(KNMS * 4 * 4);
    float* ts = (float*)alloc(KNMS * 4);
    int* tc = (int*)alloc(KNMS * 4);
    int* ti = (int*)alloc(KNMS * 4);
    int* keep = (int*)alloc(KNMS * 4);
    int* cnt = (int*)alloc(256);
    // fc0 split-K partials alias the (dead-by-then) fmt0 region: 16.8MB <= 41MB
    float* Cpart = (float*)fmt0;

    dim3 b328(32, 8, 1);
    fm_transpose<<<dim3(1250, 8, 2), b328, 0, stream>>>(fm0, fmt0, 40000);
    fm_transpose<<<dim3(313, 8, 2), b328, 0, stream>>>(fm1, fmt1, 10000);
    fm_transpose<<<dim3(79, 8, 2), b328, 0, stream>>>(fm2, fmt2, 2500);
    fm_transpose<<<dim3(20, 8, 2), b328, 0, stream>>>(fm3, fmt3, 625);
    wfc0_transpose<<<dim3(49, 8, 32), b328, 0, stream>>>(Wfc0, Wt0);
    w_transpose<<<dim3(32, 32, 1), b328, 0, stream>>>(Wfc1, Wt1, CLIN);
    w_transpose<<<dim3(32, 4, 1), b328, 0, stream>>>(Wcls, Wtc, NCLS);
    w_transpose<<<dim3(32, 12, 1), b328, 0, stream>>>(Wreg, Wtr, NCG * 4);

    roi_align<<<dim3(MPAD), 256, 0, stream>>>(props, imidx, fmt0, fmt1, fmt2, fmt3, x0);

    gemm_nt<<<dim3(8, 8, SPLITK), 256, 0, stream>>>(x0, Wt0, KDIM, 196 / SPLITK,
        Cpart, nullptr, nullptr, 0, CLIN, CLIN, (size_t)MPAD * CLIN);
    fc0_reduce<<<dim3(MPAD * CLIN / 256), 256, 0, stream>>>(Cpart, bfc0, x1);
    gemm_nt<<<dim3(8, 8, 1), 256, 0, stream>>>(x1, Wt1, CLIN, 16,
        nullptr, x2, bfc1, 1, CLIN, CLIN, 0);
    gemm_nt<<<dim3(8, 1, 1), 256, 0, stream>>>(x2, Wtc, CLIN, 16,
        logits, nullptr, bcls, 0, NCLS, NCLS, 0);
    gemm_nt<<<dim3(8, 3, 1), 256, 0, stream>>>(x2, Wtr, CLIN, 16,
        regb, nullptr, breg, 0, NCG * 4, NCG * 4, 0);

    hipMemsetAsync(cnt, 0, 4, stream);
    hipMemsetAsync(cand, 0, (size_t)CAND * 8, stream);
    decode<<<dim3(NPROP), 128, 0, stream>>>(logits, regb, props, imidx, boxes, keys);
    compact<<<dim3((NPROP * NCG + 255) / 256), 256, 0, stream>>>(keys, cand, cnt);
    sortk<<<dim3(1), 1024, 0, stream>>>(cand, sorted);
    extract<<<dim3(4), 256, 0, stream>>>(sorted, boxes, imidx, tb, toff, ts, tc, ti);
    nms<<<dim3(1), 256, 0, stream>>>(toff, ts, keep);
    writeout<<<dim3(1), 256, 0, stream>>>(tb, ts, tc, ti, keep, (float*)d_out);
}

// Round 2
// 312.443 us; speedup vs baseline: 1.8909x; 1.8909x over previous
//
#include <hip/hip_runtime.h>
#include <hip/hip_bf16.h>
#include <stdint.h>
#include <stddef.h>

typedef __hip_bfloat16 bf16;
typedef short bf16x8s __attribute__((ext_vector_type(8)));
typedef float f32x4 __attribute__((ext_vector_type(4)));
typedef unsigned long long u64;

#define NPROP 1000
#define MPAD  1024
#define NCG   80
#define NCLS  81
#define CH    256
#define KDIM  12544
#define KPAD  12800     // 50 cells * 256
#define CLIN  1024
#define NHEAD 512       // packed heads: [0,81)=cls, [128,448)=reg
#define IMGSZ 800.0f
#define SCORE_THR 0.05f
#define MIN_SIZE 0.01f
#define KNMS 1000
#define CAND 4096
#define DWH_CLAMP_F 4.135166556742356f

__device__ __forceinline__ void async_load16(const void* g, void* l) {
    __builtin_amdgcn_global_load_lds(
        (const __attribute__((address_space(1))) void*)g,
        (__attribute__((address_space(3))) void*)l, 16, 0, 0);
}

// ---------------- feature map transpose: NCHW f32 -> NHWC bf16 ----------------
__global__ void fm_transpose(const float* __restrict__ fm, bf16* __restrict__ fmt, int S) {
    __shared__ float tile[32][33];
    int b = blockIdx.z;
    int sBase = blockIdx.x * 32;
    int cBase = blockIdx.y * 32;
    int tx = threadIdx.x, ty = threadIdx.y;
#pragma unroll
    for (int i = 0; i < 4; ++i) {
        int c = cBase + ty + i * 8;
        int s = sBase + tx;
        float v = 0.f;
        if (s < S) v = fm[((size_t)(b * CH + c)) * S + s];
        tile[ty + i * 8][tx] = v;
    }
    __syncthreads();
#pragma unroll
    for (int i = 0; i < 4; ++i) {
        int s = sBase + ty + i * 8;
        int c = cBase + tx;
        if (s < S) fmt[((size_t)b * S + s) * CH + c] = __float2bfloat16(tile[tx][ty + i * 8]);
    }
}

// --------- W_fc0 (12544x1024) -> Wt0 (1024 x KPAD), k' = cell*256 + c, pad cell 49 = 0 ----
__global__ void wfc0_transpose(const float* __restrict__ W, bf16* __restrict__ Wt) {
    __shared__ float tile[32][33];
    int cell = blockIdx.x;          // 0..49 (49 = zero pad)
    int cBase = blockIdx.y * 32;
    int nBase = blockIdx.z * 32;
    int tx = threadIdx.x, ty = threadIdx.y;
#pragma unroll
    for (int i = 0; i < 4; ++i) {
        int c = cBase + ty + i * 8;
        float v = 0.f;
        if (cell < 49) v = W[(size_t)(c * 49 + cell) * CLIN + nBase + tx];
        tile[ty + i * 8][tx] = v;
    }
    __syncthreads();
#pragma unroll
    for (int i = 0; i < 4; ++i) {
        int n = nBase + ty + i * 8;
        Wt[(size_t)n * KPAD + cell * CH + cBase + tx] = __float2bfloat16(tile[tx][ty + i * 8]);
    }
}

// --------- W (1024 x ncols) -> Wt (npad x 1024) bf16 ----------
__global__ void w_transpose(const float* __restrict__ W, bf16* __restrict__ Wt, int ncols) {
    __shared__ float tile[32][33];
    int kBase = blockIdx.x * 32;
    int nBase = blockIdx.y * 32;
    int tx = threadIdx.x, ty = threadIdx.y;
#pragma unroll
    for (int i = 0; i < 4; ++i) {
        int k = kBase + ty + i * 8;
        int n = nBase + tx;
        float v = 0.f;
        if (n < ncols) v = W[(size_t)k * ncols + n];
        tile[ty + i * 8][tx] = v;
    }
    __syncthreads();
#pragma unroll
    for (int i = 0; i < 4; ++i) {
        int n = nBase + ty + i * 8;
        Wt[(size_t)n * CLIN + kBase + tx] = __float2bfloat16(tile[tx][ty + i * 8]);
    }
}

// --------- packed head weights: Wth[j][k], j<81 = Wcls col j, 128<=j<448 = Wreg col j-128 ----
__global__ void whead_transpose(const float* __restrict__ Wc, const float* __restrict__ Wr,
                                bf16* __restrict__ Wt) {
    __shared__ float tile[32][33];
    int kBase = blockIdx.x * 32;
    int jBase = blockIdx.y * 32;
    int tx = threadIdx.x, ty = threadIdx.y;
#pragma unroll
    for (int i = 0; i < 4; ++i) {
        int k = kBase + ty + i * 8;
        int j = jBase + tx;
        float v = 0.f;
        if (j < NCLS) v = Wc[(size_t)k * NCLS + j];
        else if (j >= 128 && j < 448) v = Wr[(size_t)k * (NCG * 4) + (j - 128)];
        tile[ty + i * 8][tx] = v;
    }
    __syncthreads();
#pragma unroll
    for (int i = 0; i < 4; ++i) {
        int j = jBase + ty + i * 8;
        Wt[(size_t)j * CLIN + kBase + tx] = __float2bfloat16(tile[tx][ty + i * 8]);
    }
}

// ---------------- RoI align: block = proposal, thread = channel; geometry in LDS ----------------
__global__ __launch_bounds__(256) void roi_align(
    const float* __restrict__ props, const int* __restrict__ imidx,
    const bf16* __restrict__ f0, const bf16* __restrict__ f1,
    const bf16* __restrict__ f2, const bf16* __restrict__ f3,
    bf16* __restrict__ x0) {
    int n = blockIdx.x;
    int t = threadIdx.x;
    if (n >= NPROP) {
        for (int cell = 0; cell < 50; ++cell)
            x0[(size_t)n * KPAD + cell * CH + t] = __float2bfloat16(0.f);
        return;
    }
    __shared__ int soff[196][4];
    __shared__ float sw[196][4];
    float px1 = props[n * 4 + 0], py1 = props[n * 4 + 1];
    float px2 = props[n * 4 + 2], py2 = props[n * 4 + 3];
    float w = px2 - px1, h = py2 - py1;
    float lvlf = floorf(4.0f + log2f(sqrtf(fmaxf(w * h, 1e-6f)) / 224.0f));
    int lvl = (int)fminf(fmaxf(lvlf, 2.0f), 5.0f) - 2;
    const bf16* fmt; int H, Wd; float inv;
    if (lvl == 0)      { fmt = f0; H = 200; Wd = 200; inv = 0.25f; }
    else if (lvl == 1) { fmt = f1; H = 100; Wd = 100; inv = 0.125f; }
    else if (lvl == 2) { fmt = f2; H = 50;  Wd = 50;  inv = 0.0625f; }
    else               { fmt = f3; H = 25;  Wd = 25;  inv = 0.03125f; }
    const bf16* base = fmt + (size_t)imidx[n] * H * Wd * CH;
    if (t < 196) {
        int py = t / 14, px = t - py * 14;
        float x1s = px1 * inv, y1s = py1 * inv;
        float dxs = (px2 - px1) * inv, dys = (py2 - py1) * inv;
        float fx = ((float)px + 0.5f) * (1.0f / 14.0f);
        float fy = ((float)py + 0.5f) * (1.0f / 14.0f);
        float gx = fminf(fmaxf(x1s + fx * dxs, 0.f), (float)(Wd - 1));
        float gy = fminf(fmaxf(y1s + fy * dys, 0.f), (float)(H - 1));
        float x0f = floorf(gx), y0f = floorf(gy);
        int x0i = (int)x0f, y0i = (int)y0f;
        int x1i = min(x0i + 1, Wd - 1), y1i = min(y0i + 1, H - 1);
        float lx = gx - x0f, ly = gy - y0f;
        soff[t][0] = (y0i * Wd + x0i) * CH;
        soff[t][1] = (y0i * Wd + x1i) * CH;
        soff[t][2] = (y1i * Wd + x0i) * CH;
        soff[t][3] = (y1i * Wd + x1i) * CH;
        sw[t][0] = 0.25f * (1.f - ly) * (1.f - lx);
        sw[t][1] = 0.25f * (1.f - ly) * lx;
        sw[t][2] = 0.25f * ly * (1.f - lx);
        sw[t][3] = 0.25f * ly * lx;
    }
    __syncthreads();
    for (int ci = 0; ci < 7; ++ci) {
        for (int cj = 0; cj < 7; ++cj) {
            float acc = 0.f;
#pragma unroll
            for (int sy = 0; sy < 2; ++sy) {
#pragma unroll
                for (int sx = 0; sx < 2; ++sx) {
                    int p = (ci * 2 + sy) * 14 + (cj * 2 + sx);
#pragma unroll
                    for (int q = 0; q < 4; ++q)
                        acc += sw[p][q] * __bfloat162float(base[soff[p][q] + t]);
                }
            }
            x0[(size_t)n * KPAD + (ci * 7 + cj) * CH + t] = __float2bfloat16(acc);
        }
    }
    x0[(size_t)n * KPAD + 49 * CH + t] = __float2bfloat16(0.f);
}

// -------- bf16 MFMA NT-GEMM, m97 structure: gload_lds + dbuf + 2-phase prefetch ---------
// C_partial[z] = A[128-tile] * B[128-tile]^T over z's K-chunk. lda == ldb.
#define BM 128
#define BK 64
__global__ __launch_bounds__(256) void gemm_nt(
    const bf16* __restrict__ A, const bf16* __restrict__ B,
    int lda, int kSteps, float* __restrict__ part, int ldc, size_t zStride) {
    __shared__ short Al[2][BM * BK];
    __shared__ short Bl[2][BM * BK];
    int tid = threadIdx.x;
    int bm = blockIdx.x * BM;
    int bn = blockIdx.y * BM;
    int z = blockIdx.z;
    int wave = tid >> 6, lane = tid & 63;
    int wm = (wave >> 1) * 64, wn = (wave & 1) * 64;
    int lr = lane & 15, lk = lane >> 4;
    int rowS = wave * 8 + (lane >> 3);   // staging row base
    int colS = (lane & 7) * 8;           // staging col (elements)

    f32x4 acc[4][4];
#pragma unroll
    for (int i = 0; i < 4; ++i)
#pragma unroll
        for (int j = 0; j < 4; ++j) acc[i][j] = (f32x4){0.f, 0.f, 0.f, 0.f};

    const bf16* gA = A + (size_t)(bm + rowS) * lda + colS + (size_t)z * kSteps * BK;
    const bf16* gB = B + (size_t)(bn + rowS) * lda + colS + (size_t)z * kSteps * BK;

    auto STAGE = [&](int buf, int kt) {
        size_t ko = (size_t)kt * BK;
#pragma unroll
        for (int it = 0; it < 4; ++it) {
            async_load16(gA + ko + (size_t)it * 32 * lda, &Al[buf][(it * 32 + rowS) * BK + colS]);
            async_load16(gB + ko + (size_t)it * 32 * lda, &Bl[buf][(it * 32 + rowS) * BK + colS]);
        }
    };
    auto COMPUTE = [&](int buf) {
#pragma unroll
        for (int ks = 0; ks < 2; ++ks) {
            bf16x8s af[4], bfr[4];
#pragma unroll
            for (int i = 0; i < 4; ++i)
                af[i] = *(const bf16x8s*)&Al[buf][(wm + i * 16 + lr) * BK + ks * 32 + lk * 8];
#pragma unroll
            for (int j = 0; j < 4; ++j)
                bfr[j] = *(const bf16x8s*)&Bl[buf][(wn + j * 16 + lr) * BK + ks * 32 + lk * 8];
#pragma unroll
            for (int i = 0; i < 4; ++i)
#pragma unroll
                for (int j = 0; j < 4; ++j)
                    acc[i][j] = __builtin_amdgcn_mfma_f32_16x16x32_bf16(af[i], bfr[j], acc[i][j], 0, 0, 0);
        }
    };

    int cur = 0;
    STAGE(0, 0);
    asm volatile("s_waitcnt vmcnt(0)" ::: "memory");
    __syncthreads();
    for (int kt = 0; kt < kSteps; ++kt) {
        if (kt + 1 < kSteps) STAGE(cur ^ 1, kt + 1);
        COMPUTE(cur);
        asm volatile("s_waitcnt vmcnt(0)" ::: "memory");
        __syncthreads();
        cur ^= 1;
    }
    float* outp = part + (size_t)z * zStride;
#pragma unroll
    for (int i = 0; i < 4; ++i) {
        int mbase = bm + wm + i * 16 + lk * 4;
#pragma unroll
        for (int j = 0; j < 4; ++j) {
            int ncol = bn + wn + j * 16 + lr;
#pragma unroll
            for (int r = 0; r < 4; ++r)
                outp[(size_t)(mbase + r) * ldc + ncol] = acc[i][j][r];
        }
    }
}

// ---------------- split-K reduce (+bias, +relu) -> bf16 or f32 ----------------
__global__ void reduceK(const float* __restrict__ part, int nsplit, size_t zStride,
                        const float* __restrict__ bias, int colMask, int relu,
                        bf16* __restrict__ outB, float* __restrict__ outF) {
    int idx = blockIdx.x * 256 + threadIdx.x;
    float v = bias ? bias[idx & colMask] : 0.f;
    for (int s = 0; s < nsplit; ++s) v += part[(size_t)s * zStride + idx];
    if (relu) v = fmaxf(v, 0.f);
    if (outB) outB[idx] = __float2bfloat16(v);
    else outF[idx] = v;
}

// ---------------- softmax + box decode + key build ----------------
__global__ __launch_bounds__(128) void decode(
    const float* __restrict__ heads,
    const float* __restrict__ bcls, const float* __restrict__ breg,
    const float* __restrict__ props, const int* __restrict__ imidx,
    float* __restrict__ boxes, u64* __restrict__ keys) {
    __shared__ float red[128];
    int n = blockIdx.x, t = threadIdx.x;
    float l = (t < NCLS) ? heads[(size_t)n * NHEAD + t] + bcls[t] : -1e30f;
    red[t] = l; __syncthreads();
    for (int s = 64; s > 0; s >>= 1) { if (t < s) red[t] = fmaxf(red[t], red[t + s]); __syncthreads(); }
    float mx = red[0]; __syncthreads();
    float e = (t < NCLS) ? expf(l - mx) : 0.f;
    red[t] = e; __syncthreads();
    for (int s = 64; s > 0; s >>= 1) { if (t < s) red[t] += red[t + s]; __syncthreads(); }
    float denom = red[0];
    if (t >= NCG) return;
    float score = e / denom;
    float px1 = props[n * 4 + 0], py1 = props[n * 4 + 1];
    float px2 = props[n * 4 + 2], py2 = props[n * 4 + 3];
    float pw = px2 - px1, ph = py2 - py1;
    float pcx = px1 + 0.5f * pw, pcy = py1 + 0.5f * ph;
    const float* r4 = heads + (size_t)n * NHEAD + 128 + t * 4;
    float dx = (r4[0] + breg[t * 4 + 0]) * 0.1f;
    float dy = (r4[1] + breg[t * 4 + 1]) * 0.1f;
    float dw = fminf((r4[2] + breg[t * 4 + 2]) * 0.2f, DWH_CLAMP_F);
    float dh = fminf((r4[3] + breg[t * 4 + 3]) * 0.2f, DWH_CLAMP_F);
    float cx = pcx + dx * pw, cy = pcy + dy * ph;
    float bw = pw * expf(dw), bh = ph * expf(dh);
    float x1 = fminf(fmaxf(cx - 0.5f * bw, 0.f), IMGSZ);
    float y1 = fminf(fmaxf(cy - 0.5f * bh, 0.f), IMGSZ);
    float x2 = fminf(fmaxf(cx + 0.5f * bw, 0.f), IMGSZ);
    float y2 = fminf(fmaxf(cy + 0.5f * bh, 0.f), IMGSZ);
    int idx = n * NCG + t;
    float* bo = boxes + (size_t)idx * 4;
    bo[0] = x1; bo[1] = y1; bo[2] = x2; bo[3] = y2;
    bool valid = (score > SCORE_THR) && ((x2 - x1) >= MIN_SIZE) && ((y2 - y1) >= MIN_SIZE);
    u64 key = 0ull;
    if (valid) key = ((u64)__float_as_uint(score) << 17) | (u64)(0x1FFFFu - (unsigned)idx);
    keys[idx] = key;
}

__global__ void compact(const u64* __restrict__ keys, u64* __restrict__ cand, int* __restrict__ cnt) {
    int i = blockIdx.x * 256 + threadIdx.x;
    if (i >= NPROP * NCG) return;
    u64 k = keys[i];
    if (k) { int p = atomicAdd(cnt, 1); if (p < CAND) cand[p] = k; }
}

// ---------------- bitonic descending sort, dynamic size, one block ----------------
__global__ __launch_bounds__(1024) void sortk(const u64* __restrict__ cand, u64* __restrict__ sorted,
                                              const int* __restrict__ cntp) {
    __shared__ u64 s[CAND];
    int t = threadIdx.x;
    int n = min(*cntp, CAND);
    if (n == 0) { sorted[t] = 0ull; return; }   // extract reads first 1000 only
    int NS = (n <= 1024) ? 1024 : ((n <= 2048) ? 2048 : 4096);
    int E = NS >> 10;
    for (int p = 0; p < E; ++p) s[t + p * 1024] = cand[t + p * 1024];
    __syncthreads();
    for (int k = 2; k <= NS; k <<= 1) {
        for (int j = k >> 1; j > 0; j >>= 1) {
            for (int p = 0; p < E; ++p) {
                int i = t + p * 1024;
                int l = i ^ j;
                if (l > i) {
                    u64 a = s[i], b = s[l];
                    bool desc = ((i & k) == 0);
                    if (desc ? (a < b) : (a > b)) { s[i] = b; s[l] = a; }
                }
            }
            __syncthreads();
        }
    }
    for (int p = 0; p < E; ++p) sorted[t + p * 1024] = s[t + p * 1024];
}

// ---------------- gather top-1000 attributes ----------------
__global__ void extract(const u64* __restrict__ sorted, const float* __restrict__ boxes,
                        const int* __restrict__ imidx,
                        float* __restrict__ tb, float* __restrict__ toff,
                        float* __restrict__ ts, int* __restrict__ tc, int* __restrict__ ti) {
    int s = blockIdx.x * 256 + threadIdx.x;
    if (s >= KNMS) return;
    u64 key = sorted[s];
    if (key == 0ull) {
        ts[s] = -1.f; tc[s] = -1; ti[s] = -1;
        for (int d = 0; d < 4; ++d) { tb[s * 4 + d] = 0.f; toff[s * 4 + d] = 0.f; }
        return;
    }
    unsigned idx = 0x1FFFFu - (unsigned)(key & 0x1FFFFull);
    float score = __uint_as_float((unsigned)(key >> 17));
    int n = idx / NCG, c = idx - n * NCG;
    int im = imidx[n];
    float off = (float)(im * NCG + c) * 1000.0f;
    for (int d = 0; d < 4; ++d) {
        float v = boxes[(size_t)idx * 4 + d];
        tb[s * 4 + d] = v;
        toff[s * 4 + d] = v + off;
    }
    ts[s] = score; tc[s] = c; ti[s] = im;
}

// ---------------- greedy NMS, single block ----------------
__global__ __launch_bounds__(256) void nms(const float* __restrict__ toff, const float* __restrict__ ts,
                                           int* __restrict__ keep) {
    __shared__ float4 bx[KNMS];
    __shared__ int kp[KNMS];
    __shared__ int Vsh;
    int t = threadIdx.x;
    if (t == 0) Vsh = KNMS;
    __syncthreads();
    for (int s = t; s < KNMS; s += 256) {
        bx[s] = ((const float4*)toff)[s];
        bool ok = ts[s] > 0.f;
        kp[s] = ok ? 1 : 0;
        if (!ok) atomicMin(&Vsh, s);
    }
    __syncthreads();
    int V = Vsh;
    for (int i = 0; i < V; ++i) {
        if (kp[i]) {
            float4 bi = bx[i];
            float ai = (bi.z - bi.x) * (bi.w - bi.y);
            for (int j2 = i + 1 + t; j2 < V; j2 += 256) {
                if (!kp[j2]) continue;
                float4 bj = bx[j2];
                float xx1 = fmaxf(bi.x, bj.x), yy1 = fmaxf(bi.y, bj.y);
                float xx2 = fminf(bi.z, bj.z), yy2 = fminf(bi.w, bj.w);
                float iw = fmaxf(xx2 - xx1, 0.f), ih = fmaxf(yy2 - yy1, 0.f);
                float inter = iw * ih;
                float aj = (bj.z - bj.x) * (bj.w - bj.y);
                float iou = inter / fmaxf(ai + aj - inter, 1e-9f);
                if (iou > 0.5f) kp[j2] = 0;
            }
        }
        __syncthreads();
    }
    for (int s = t; s < KNMS; s += 256) keep[s] = kp[s];
}

// ---------------- per-image top-100 writeout ----------------
__global__ __launch_bounds__(256) void writeout(
    const float* __restrict__ tb, const float* __restrict__ ts,
    const int* __restrict__ tc, const int* __restrict__ ti,
    const int* __restrict__ keep, float* __restrict__ out) {
    __shared__ short flag[KNMS];
    __shared__ int sel[2][100];
    __shared__ int cnts[2];
    int t = threadIdx.x;
    for (int s = t; s < KNMS; s += 256)
        flag[s] = (keep[s] && ts[s] > 0.f) ? (short)(ti[s] + 1) : (short)0;
    __syncthreads();
    if (t == 0) {
        int c0 = 0, c1 = 0;
        for (int s = 0; s < KNMS; ++s) {
            int f = flag[s];
            if (f == 1) { if (c0 < 100) sel[0][c0++] = s; }
            else if (f == 2) { if (c1 < 100) sel[1][c1++] = s; }
        }
        cnts[0] = c0; cnts[1] = c1;
    }
    __syncthreads();
    for (int r = t; r < 200; r += 256) {
        int im = r / 100, q = r - im * 100;
        if (q < cnts[im]) {
            int s = sel[im][q];
            for (int d = 0; d < 4; ++d) out[(im * 100 + q) * 4 + d] = tb[s * 4 + d];
            out[800 + im * 100 + q] = ts[s];
            out[1000 + im * 100 + q] = (float)tc[s];
        } else {
            for (int d = 0; d < 4; ++d) out[(im * 100 + q) * 4 + d] = 0.f;
            out[800 + im * 100 + q] = 0.f;
            out[1000 + im * 100 + q] = -1.0f;
        }
    }
}

// =====================================================================
extern "C" void kernel_launch(void* const* d_in, const int* in_sizes, int n_in,
                              void* d_out, int out_size, void* d_ws, size_t ws_size,
                              hipStream_t stream) {
    (void)in_sizes; (void)n_in; (void)out_size; (void)ws_size;
    const float* props = (const float*)d_in[0];
    const int*   imidx = (const int*)d_in[1];
    const float* fm0 = (const float*)d_in[2];
    const float* fm1 = (const float*)d_in[3];
    const float* fm2 = (const float*)d_in[4];
    const float* fm3 = (const float*)d_in[5];
    const float* Wfc0 = (const float*)d_in[6];
    const float* bfc0 = (const float*)d_in[7];
    const float* Wfc1 = (const float*)d_in[8];
    const float* bfc1 = (const float*)d_in[9];
    const float* Wcls = (const float*)d_in[10];
    const float* bcls = (const float*)d_in[11];
    const float* Wreg = (const float*)d_in[12];
    const float* breg = (const float*)d_in[13];

    char* p = (char*)d_ws;
    auto alloc = [&](size_t bytes) { char* r = p; p += (bytes + 255) & ~(size_t)255; return r; };

    bf16* fmt0 = (bf16*)alloc((size_t)2 * 40000 * CH * 2);  // 41 MB; re-used as split-K scratch
    bf16* fmt1 = (bf16*)alloc((size_t)2 * 10000 * CH * 2);
    bf16* fmt2 = (bf16*)alloc((size_t)2 * 2500 * CH * 2);
    bf16* fmt3 = (bf16*)alloc((size_t)2 * 625 * CH * 2);
    bf16* Wt0 = (bf16*)alloc((size_t)CLIN * KPAD * 2);
    bf16* Wt1 = (bf16*)alloc((size_t)CLIN * CLIN * 2);
    bf16* Wth = (bf16*)alloc((size_t)NHEAD * CLIN * 2);
    bf16* x0 = (bf16*)alloc((size_t)MPAD * KPAD * 2);
    bf16* x1 = (bf16*)alloc((size_t)MPAD * CLIN * 2);
    bf16* x2 = (bf16*)alloc((size_t)MPAD * CLIN * 2);
    float* heads = (float*)alloc((size_t)MPAD * NHEAD * 4);
    float* boxes = (float*)alloc((size_t)NPROP * NCG * 4 * 4);
    u64* keys = (u64*)alloc((size_t)NPROP * NCG * 8);
    u64* cand = (u64*)alloc((size_t)CAND * 8);
    u64* sorted = (u64*)alloc((size_t)CAND * 8);
    float* tb = (float*)alloc(KNMS * 4 * 4);
    float* toff = (float*)alloc(KNMS * 4 * 4);
    float* ts = (float*)alloc(KNMS * 4);
    int* tc = (int*)alloc(KNMS * 4);
    int* ti = (int*)alloc(KNMS * 4);
    int* keep = (int*)alloc(KNMS * 4);
    int* cnt = (int*)alloc(256);
    // split-K partials alias the (dead-by-then) fmt0 region (41 MB):
    //   fc0: 8*4.2 = 33.6 MB ; fc1: 16.8 MB ; heads: 16.8 MB  (sequential uses)
    float* Cpart = (float*)fmt0;

    dim3 b328(32, 8, 1);
    fm_transpose<<<dim3(1250, 8, 2), b328, 0, stream>>>(fm0, fmt0, 40000);
    fm_transpose<<<dim3(313, 8, 2), b328, 0, stream>>>(fm1, fmt1, 10000);
    fm_transpose<<<dim3(79, 8, 2), b328, 0, stream>>>(fm2, fmt2, 2500);
    fm_transpose<<<dim3(20, 8, 2), b328, 0, stream>>>(fm3, fmt3, 625);
    wfc0_transpose<<<dim3(50, 8, 32), b328, 0, stream>>>(Wfc0, Wt0);
    w_transpose<<<dim3(32, 32, 1), b328, 0, stream>>>(Wfc1, Wt1, CLIN);
    whead_transpose<<<dim3(32, 16, 1), b328, 0, stream>>>(Wcls, Wreg, Wth);

    roi_align<<<dim3(MPAD), 256, 0, stream>>>(props, imidx, fmt0, fmt1, fmt2, fmt3, x0);

    // fc0: M=1024 N=1024 K=12800, split-K 8 (25 steps/z), grid 512 blocks
    gemm_nt<<<dim3(8, 8, 8), 256, 0, stream>>>(x0, Wt0, KPAD, 25, Cpart, CLIN, (size_t)MPAD * CLIN);
    reduceK<<<dim3(MPAD * CLIN / 256), 256, 0, stream>>>(Cpart, 8, (size_t)MPAD * CLIN,
        bfc0, CLIN - 1, 1, x1, nullptr);
    // fc1: K=1024, split-K 4 (4 steps/z), 256 blocks
    gemm_nt<<<dim3(8, 8, 4), 256, 0, stream>>>(x1, Wt1, CLIN, 4, Cpart, CLIN, (size_t)MPAD * CLIN);
    reduceK<<<dim3(MPAD * CLIN / 256), 256, 0, stream>>>(Cpart, 4, (size_t)MPAD * CLIN,
        bfc1, CLIN - 1, 1, x2, nullptr);
    // heads: N=512, split-K 8 (2 steps/z), 256 blocks; bias folded into decode
    gemm_nt<<<dim3(8, 4, 8), 256, 0, stream>>>(x2, Wth, CLIN, 2, Cpart, NHEAD, (size_t)MPAD * NHEAD);
    reduceK<<<dim3(MPAD * NHEAD / 256), 256, 0, stream>>>(Cpart, 8, (size_t)MPAD * NHEAD,
        nullptr, 0, 0, nullptr, heads);

    hipMemsetAsync(cnt, 0, 4, stream);
    hipMemsetAsync(cand, 0, (size_t)CAND * 8, stream);
    decode<<<dim3(NPROP), 128, 0, stream>>>(heads, bcls, breg, props, imidx, boxes, keys);
    compact<<<dim3((NPROP * NCG + 255) / 256), 256, 0, stream>>>(keys, cand, cnt);
    sortk<<<dim3(1), 1024, 0, stream>>>(cand, sorted, cnt);
    extract<<<dim3(4), 256, 0, stream>>>(sorted, boxes, imidx, tb, toff, ts, tc, ti);
    nms<<<dim3(1), 256, 0, stream>>>(toff, ts, keep);
    writeout<<<dim3(1), 256, 0, stream>>>(tb, ts, tc, ti, keep, (float*)d_out);
}

// Round 3
// 226.409 us; speedup vs baseline: 2.6094x; 1.3800x over previous
//
#include <hip/hip_runtime.h>
#include <hip/hip_bf16.h>
#include <stdint.h>
#include <stddef.h>

typedef __hip_bfloat16 bf16;
typedef short bf16x8s __attribute__((ext_vector_type(8)));
typedef float f32x4 __attribute__((ext_vector_type(4)));
typedef unsigned long long u64;

#define NPROP 1000
#define MPAD  1024
#define NCG   80
#define NCLS  81
#define CH    256
#define KDIM  12544
#define KPAD  12800     // 50 cells * 256
#define CLIN  1024
#define NHEAD 512       // packed heads: [0,81)=cls, [128,448)=reg
#define IMGSZ 800.0f
#define SCORE_THR 0.05f
#define MIN_SIZE 0.01f
#define KNMS 1000
#define CAND 4096
#define DWH_CLAMP_F 4.135166556742356f

__device__ __forceinline__ void async_load16(const void* g, void* l) {
    __builtin_amdgcn_global_load_lds(
        (const __attribute__((address_space(1))) void*)g,
        (__attribute__((address_space(3))) void*)l, 16, 0, 0);
}

// ---------------- feature map transpose: NCHW f32 -> NHWC bf16 ----------------
__global__ void fm_transpose(const float* __restrict__ fm, bf16* __restrict__ fmt, int S) {
    __shared__ float tile[32][33];
    int b = blockIdx.z;
    int sBase = blockIdx.x * 32;
    int cBase = blockIdx.y * 32;
    int tx = threadIdx.x, ty = threadIdx.y;
#pragma unroll
    for (int i = 0; i < 4; ++i) {
        int c = cBase + ty + i * 8;
        int s = sBase + tx;
        float v = 0.f;
        if (s < S) v = fm[((size_t)(b * CH + c)) * S + s];
        tile[ty + i * 8][tx] = v;
    }
    __syncthreads();
#pragma unroll
    for (int i = 0; i < 4; ++i) {
        int s = sBase + ty + i * 8;
        int c = cBase + tx;
        if (s < S) fmt[((size_t)b * S + s) * CH + c] = __float2bfloat16(tile[tx][ty + i * 8]);
    }
}

// --------- W_fc0 (12544x1024) -> Wt0 (1024 x KPAD), k' = cell*256 + c, pad cell 49 = 0 ----
__global__ void wfc0_transpose(const float* __restrict__ W, bf16* __restrict__ Wt) {
    __shared__ float tile[32][33];
    int cell = blockIdx.x;          // 0..49 (49 = zero pad)
    int cBase = blockIdx.y * 32;
    int nBase = blockIdx.z * 32;
    int tx = threadIdx.x, ty = threadIdx.y;
#pragma unroll
    for (int i = 0; i < 4; ++i) {
        int c = cBase + ty + i * 8;
        float v = 0.f;
        if (cell < 49) v = W[(size_t)(c * 49 + cell) * CLIN + nBase + tx];
        tile[ty + i * 8][tx] = v;
    }
    __syncthreads();
#pragma unroll
    for (int i = 0; i < 4; ++i) {
        int n = nBase + ty + i * 8;
        Wt[(size_t)n * KPAD + cell * CH + cBase + tx] = __float2bfloat16(tile[tx][ty + i * 8]);
    }
}

// --------- W (1024 x ncols) -> Wt (npad x 1024) bf16 ----------
__global__ void w_transpose(const float* __restrict__ W, bf16* __restrict__ Wt, int ncols) {
    __shared__ float tile[32][33];
    int kBase = blockIdx.x * 32;
    int nBase = blockIdx.y * 32;
    int tx = threadIdx.x, ty = threadIdx.y;
#pragma unroll
    for (int i = 0; i < 4; ++i) {
        int k = kBase + ty + i * 8;
        int n = nBase + tx;
        float v = 0.f;
        if (n < ncols) v = W[(size_t)k * ncols + n];
        tile[ty + i * 8][tx] = v;
    }
    __syncthreads();
#pragma unroll
    for (int i = 0; i < 4; ++i) {
        int n = nBase + ty + i * 8;
        Wt[(size_t)n * CLIN + kBase + tx] = __float2bfloat16(tile[tx][ty + i * 8]);
    }
}

// --------- packed head weights: Wth[j][k], j<81 = Wcls col j, 128<=j<448 = Wreg col j-128 ----
__global__ void whead_transpose(const float* __restrict__ Wc, const float* __restrict__ Wr,
                                bf16* __restrict__ Wt) {
    __shared__ float tile[32][33];
    int kBase = blockIdx.x * 32;
    int jBase = blockIdx.y * 32;
    int tx = threadIdx.x, ty = threadIdx.y;
#pragma unroll
    for (int i = 0; i < 4; ++i) {
        int k = kBase + ty + i * 8;
        int j = jBase + tx;
        float v = 0.f;
        if (j < NCLS) v = Wc[(size_t)k * NCLS + j];
        else if (j >= 128 && j < 448) v = Wr[(size_t)k * (NCG * 4) + (j - 128)];
        tile[ty + i * 8][tx] = v;
    }
    __syncthreads();
#pragma unroll
    for (int i = 0; i < 4; ++i) {
        int j = jBase + ty + i * 8;
        Wt[(size_t)j * CLIN + kBase + tx] = __float2bfloat16(tile[tx][ty + i * 8]);
    }
}

// ---------------- RoI align: block = proposal, thread = channel; geometry in LDS ----------------
__global__ __launch_bounds__(256) void roi_align(
    const float* __restrict__ props, const int* __restrict__ imidx,
    const bf16* __restrict__ f0, const bf16* __restrict__ f1,
    const bf16* __restrict__ f2, const bf16* __restrict__ f3,
    bf16* __restrict__ x0) {
    int n = blockIdx.x;
    int t = threadIdx.x;
    if (n >= NPROP) {
        for (int cell = 0; cell < 50; ++cell)
            x0[(size_t)n * KPAD + cell * CH + t] = __float2bfloat16(0.f);
        return;
    }
    __shared__ int soff[196][4];
    __shared__ float sw[196][4];
    float px1 = props[n * 4 + 0], py1 = props[n * 4 + 1];
    float px2 = props[n * 4 + 2], py2 = props[n * 4 + 3];
    float w = px2 - px1, h = py2 - py1;
    float lvlf = floorf(4.0f + log2f(sqrtf(fmaxf(w * h, 1e-6f)) / 224.0f));
    int lvl = (int)fminf(fmaxf(lvlf, 2.0f), 5.0f) - 2;
    const bf16* fmt; int H, Wd; float inv;
    if (lvl == 0)      { fmt = f0; H = 200; Wd = 200; inv = 0.25f; }
    else if (lvl == 1) { fmt = f1; H = 100; Wd = 100; inv = 0.125f; }
    else if (lvl == 2) { fmt = f2; H = 50;  Wd = 50;  inv = 0.0625f; }
    else               { fmt = f3; H = 25;  Wd = 25;  inv = 0.03125f; }
    const bf16* base = fmt + (size_t)imidx[n] * H * Wd * CH;
    if (t < 196) {
        int py = t / 14, px = t - py * 14;
        float x1s = px1 * inv, y1s = py1 * inv;
        float dxs = (px2 - px1) * inv, dys = (py2 - py1) * inv;
        float fx = ((float)px + 0.5f) * (1.0f / 14.0f);
        float fy = ((float)py + 0.5f) * (1.0f / 14.0f);
        float gx = fminf(fmaxf(x1s + fx * dxs, 0.f), (float)(Wd - 1));
        float gy = fminf(fmaxf(y1s + fy * dys, 0.f), (float)(H - 1));
        float x0f = floorf(gx), y0f = floorf(gy);
        int x0i = (int)x0f, y0i = (int)y0f;
        int x1i = min(x0i + 1, Wd - 1), y1i = min(y0i + 1, H - 1);
        float lx = gx - x0f, ly = gy - y0f;
        soff[t][0] = (y0i * Wd + x0i) * CH;
        soff[t][1] = (y0i * Wd + x1i) * CH;
        soff[t][2] = (y1i * Wd + x0i) * CH;
        soff[t][3] = (y1i * Wd + x1i) * CH;
        sw[t][0] = 0.25f * (1.f - ly) * (1.f - lx);
        sw[t][1] = 0.25f * (1.f - ly) * lx;
        sw[t][2] = 0.25f * ly * (1.f - lx);
        sw[t][3] = 0.25f * ly * lx;
    }
    __syncthreads();
    for (int ci = 0; ci < 7; ++ci) {
        for (int cj = 0; cj < 7; ++cj) {
            float acc = 0.f;
#pragma unroll
            for (int sy = 0; sy < 2; ++sy) {
#pragma unroll
                for (int sx = 0; sx < 2; ++sx) {
                    int p = (ci * 2 + sy) * 14 + (cj * 2 + sx);
#pragma unroll
                    for (int q = 0; q < 4; ++q)
                        acc += sw[p][q] * __bfloat162float(base[soff[p][q] + t]);
                }
            }
            x0[(size_t)n * KPAD + (ci * 7 + cj) * CH + t] = __float2bfloat16(acc);
        }
    }
    x0[(size_t)n * KPAD + 49 * CH + t] = __float2bfloat16(0.f);
}

// -------- bf16 MFMA NT-GEMM, m97 structure: gload_lds + dbuf + 2-phase prefetch ---------
#define BM 128
#define BK 64
__global__ __launch_bounds__(256) void gemm_nt(
    const bf16* __restrict__ A, const bf16* __restrict__ B,
    int lda, int kSteps, float* __restrict__ part, int ldc, size_t zStride) {
    __shared__ short Al[2][BM * BK];
    __shared__ short Bl[2][BM * BK];
    int tid = threadIdx.x;
    int bm = blockIdx.x * BM;
    int bn = blockIdx.y * BM;
    int z = blockIdx.z;
    int wave = tid >> 6, lane = tid & 63;
    int wm = (wave >> 1) * 64, wn = (wave & 1) * 64;
    int lr = lane & 15, lk = lane >> 4;
    int rowS = wave * 8 + (lane >> 3);
    int colS = (lane & 7) * 8;

    f32x4 acc[4][4];
#pragma unroll
    for (int i = 0; i < 4; ++i)
#pragma unroll
        for (int j = 0; j < 4; ++j) acc[i][j] = (f32x4){0.f, 0.f, 0.f, 0.f};

    const bf16* gA = A + (size_t)(bm + rowS) * lda + colS + (size_t)z * kSteps * BK;
    const bf16* gB = B + (size_t)(bn + rowS) * lda + colS + (size_t)z * kSteps * BK;

    auto STAGE = [&](int buf, int kt) {
        size_t ko = (size_t)kt * BK;
#pragma unroll
        for (int it = 0; it < 4; ++it) {
            async_load16(gA + ko + (size_t)it * 32 * lda, &Al[buf][(it * 32 + rowS) * BK + colS]);
            async_load16(gB + ko + (size_t)it * 32 * lda, &Bl[buf][(it * 32 + rowS) * BK + colS]);
        }
    };
    auto COMPUTE = [&](int buf) {
#pragma unroll
        for (int ks = 0; ks < 2; ++ks) {
            bf16x8s af[4], bfr[4];
#pragma unroll
            for (int i = 0; i < 4; ++i)
                af[i] = *(const bf16x8s*)&Al[buf][(wm + i * 16 + lr) * BK + ks * 32 + lk * 8];
#pragma unroll
            for (int j = 0; j < 4; ++j)
                bfr[j] = *(const bf16x8s*)&Bl[buf][(wn + j * 16 + lr) * BK + ks * 32 + lk * 8];
#pragma unroll
            for (int i = 0; i < 4; ++i)
#pragma unroll
                for (int j = 0; j < 4; ++j)
                    acc[i][j] = __builtin_amdgcn_mfma_f32_16x16x32_bf16(af[i], bfr[j], acc[i][j], 0, 0, 0);
        }
    };

    int cur = 0;
    STAGE(0, 0);
    asm volatile("s_waitcnt vmcnt(0)" ::: "memory");
    __syncthreads();
    for (int kt = 0; kt < kSteps; ++kt) {
        if (kt + 1 < kSteps) STAGE(cur ^ 1, kt + 1);
        COMPUTE(cur);
        asm volatile("s_waitcnt vmcnt(0)" ::: "memory");
        __syncthreads();
        cur ^= 1;
    }
    float* outp = part + (size_t)z * zStride;
#pragma unroll
    for (int i = 0; i < 4; ++i) {
        int mbase = bm + wm + i * 16 + lk * 4;
#pragma unroll
        for (int j = 0; j < 4; ++j) {
            int ncol = bn + wn + j * 16 + lr;
#pragma unroll
            for (int r = 0; r < 4; ++r)
                outp[(size_t)(mbase + r) * ldc + ncol] = acc[i][j][r];
        }
    }
}

// ---------------- split-K reduce (+bias, +relu) -> bf16 or f32 ----------------
__global__ void reduceK(const float* __restrict__ part, int nsplit, size_t zStride,
                        const float* __restrict__ bias, int colMask, int relu,
                        bf16* __restrict__ outB, float* __restrict__ outF) {
    int idx = blockIdx.x * 256 + threadIdx.x;
    float v = bias ? bias[idx & colMask] : 0.f;
    for (int s = 0; s < nsplit; ++s) v += part[(size_t)s * zStride + idx];
    if (relu) v = fmaxf(v, 0.f);
    if (outB) outB[idx] = __float2bfloat16(v);
    else outF[idx] = v;
}

// ---------------- softmax + box decode + key build ----------------
__global__ __launch_bounds__(128) void decode(
    const float* __restrict__ heads,
    const float* __restrict__ bcls, const float* __restrict__ breg,
    const float* __restrict__ props, const int* __restrict__ imidx,
    float* __restrict__ boxes, u64* __restrict__ keys) {
    __shared__ float red[128];
    int n = blockIdx.x, t = threadIdx.x;
    float l = (t < NCLS) ? heads[(size_t)n * NHEAD + t] + bcls[t] : -1e30f;
    red[t] = l; __syncthreads();
    for (int s = 64; s > 0; s >>= 1) { if (t < s) red[t] = fmaxf(red[t], red[t + s]); __syncthreads(); }
    float mx = red[0]; __syncthreads();
    float e = (t < NCLS) ? expf(l - mx) : 0.f;
    red[t] = e; __syncthreads();
    for (int s = 64; s > 0; s >>= 1) { if (t < s) red[t] += red[t + s]; __syncthreads(); }
    float denom = red[0];
    if (t >= NCG) return;
    float score = e / denom;
    float px1 = props[n * 4 + 0], py1 = props[n * 4 + 1];
    float px2 = props[n * 4 + 2], py2 = props[n * 4 + 3];
    float pw = px2 - px1, ph = py2 - py1;
    float pcx = px1 + 0.5f * pw, pcy = py1 + 0.5f * ph;
    const float* r4 = heads + (size_t)n * NHEAD + 128 + t * 4;
    float dx = (r4[0] + breg[t * 4 + 0]) * 0.1f;
    float dy = (r4[1] + breg[t * 4 + 1]) * 0.1f;
    float dw = fminf((r4[2] + breg[t * 4 + 2]) * 0.2f, DWH_CLAMP_F);
    float dh = fminf((r4[3] + breg[t * 4 + 3]) * 0.2f, DWH_CLAMP_F);
    float cx = pcx + dx * pw, cy = pcy + dy * ph;
    float bw = pw * expf(dw), bh = ph * expf(dh);
    float x1 = fminf(fmaxf(cx - 0.5f * bw, 0.f), IMGSZ);
    float y1 = fminf(fmaxf(cy - 0.5f * bh, 0.f), IMGSZ);
    float x2 = fminf(fmaxf(cx + 0.5f * bw, 0.f), IMGSZ);
    float y2 = fminf(fmaxf(cy + 0.5f * bh, 0.f), IMGSZ);
    int idx = n * NCG + t;
    float* bo = boxes + (size_t)idx * 4;
    bo[0] = x1; bo[1] = y1; bo[2] = x2; bo[3] = y2;
    bool valid = (score > SCORE_THR) && ((x2 - x1) >= MIN_SIZE) && ((y2 - y1) >= MIN_SIZE);
    u64 key = 0ull;
    if (valid) key = ((u64)__float_as_uint(score) << 17) | (u64)(0x1FFFFu - (unsigned)idx);
    keys[idx] = key;
}

__global__ void compact(const u64* __restrict__ keys, u64* __restrict__ cand, int* __restrict__ cnt) {
    int i = blockIdx.x * 256 + threadIdx.x;
    if (i >= NPROP * NCG) return;
    u64 k = keys[i];
    if (k) { int p = atomicAdd(cnt, 1); if (p < CAND) cand[p] = k; }
}

// ---------------- bitonic descending sort, dynamic size, one block ----------------
__global__ __launch_bounds__(1024) void sortk(const u64* __restrict__ cand, u64* __restrict__ sorted,
                                              const int* __restrict__ cntp) {
    __shared__ u64 s[CAND];
    int t = threadIdx.x;
    int n = min(*cntp, CAND);
    if (n == 0) { sorted[t] = 0ull; return; }
    int NS = (n <= 1024) ? 1024 : ((n <= 2048) ? 2048 : 4096);
    int E = NS >> 10;
    for (int p = 0; p < E; ++p) s[t + p * 1024] = cand[t + p * 1024];
    __syncthreads();
    for (int k = 2; k <= NS; k <<= 1) {
        for (int j = k >> 1; j > 0; j >>= 1) {
            for (int p = 0; p < E; ++p) {
                int i = t + p * 1024;
                int l = i ^ j;
                if (l > i) {
                    u64 a = s[i], b = s[l];
                    bool desc = ((i & k) == 0);
                    if (desc ? (a < b) : (a > b)) { s[i] = b; s[l] = a; }
                }
            }
            __syncthreads();
        }
    }
    for (int p = 0; p < E; ++p) sorted[t + p * 1024] = s[t + p * 1024];
}

// ---------------- gather top-1000 attributes ----------------
__global__ void extract(const u64* __restrict__ sorted, const float* __restrict__ boxes,
                        const int* __restrict__ imidx,
                        float* __restrict__ tb, float* __restrict__ toff,
                        float* __restrict__ ts, int* __restrict__ tc, int* __restrict__ ti) {
    int s = blockIdx.x * 256 + threadIdx.x;
    if (s >= KNMS) return;
    u64 key = sorted[s];
    if (key == 0ull) {
        ts[s] = -1.f; tc[s] = -1; ti[s] = -1;
        for (int d = 0; d < 4; ++d) { tb[s * 4 + d] = 0.f; toff[s * 4 + d] = 0.f; }
        return;
    }
    unsigned idx = 0x1FFFFu - (unsigned)(key & 0x1FFFFull);
    float score = __uint_as_float((unsigned)(key >> 17));
    int n = idx / NCG, c = idx - n * NCG;
    int im = imidx[n];
    float off = (float)(im * NCG + c) * 1000.0f;
    for (int d = 0; d < 4; ++d) {
        float v = boxes[(size_t)idx * 4 + d];
        tb[s * 4 + d] = v;
        toff[s * 4 + d] = v + off;
    }
    ts[s] = score; tc[s] = c; ti[s] = im;
}

// ------------- fused greedy NMS + parallel per-image top-100 writeout -------------
__global__ __launch_bounds__(256) void nms_write(
    const float* __restrict__ toff, const float* __restrict__ tb,
    const float* __restrict__ ts, const int* __restrict__ tc, const int* __restrict__ ti,
    float* __restrict__ out) {
    __shared__ float4 bx[KNMS];
    __shared__ int kp[KNMS];
    __shared__ int Vsh;
    __shared__ unsigned scan[256];
    int t = threadIdx.x;
    if (t == 0) Vsh = KNMS;
    __syncthreads();
    for (int s = t; s < KNMS; s += 256) {
        bx[s] = ((const float4*)toff)[s];
        bool ok = ts[s] > 0.f;
        kp[s] = ok ? 1 : 0;
        if (!ok) atomicMin(&Vsh, s);
    }
    __syncthreads();
    int V = Vsh;   // valid entries form a prefix (sorted descending)
    for (int i = 0; i < V; ++i) {
        if (kp[i]) {
            float4 bi = bx[i];
            float ai = (bi.z - bi.x) * (bi.w - bi.y);
            for (int j2 = i + 1 + t; j2 < V; j2 += 256) {
                if (!kp[j2]) continue;
                float4 bj = bx[j2];
                float xx1 = fmaxf(bi.x, bj.x), yy1 = fmaxf(bi.y, bj.y);
                float xx2 = fminf(bi.z, bj.z), yy2 = fminf(bi.w, bj.w);
                float iw = fmaxf(xx2 - xx1, 0.f), ih = fmaxf(yy2 - yy1, 0.f);
                float inter = iw * ih;
                float aj = (bj.z - bj.x) * (bj.w - bj.y);
                float iou = inter / fmaxf(ai + aj - inter, 1e-9f);
                if (iou > 0.5f) kp[j2] = 0;
            }
        }
        __syncthreads();
    }
    // defaults for all 200 output slots
    for (int r = t; r < 200; r += 256) {
        int slot = r;
        for (int d = 0; d < 4; ++d) out[slot * 4 + d] = 0.f;
        out[800 + slot] = 0.f;
        out[1000 + slot] = -1.0f;
    }
    // parallel stable compaction: thread t owns entries [4t, 4t+4)
    unsigned loc[4];     // packed per-entry flag: 1 (im0) / 0x10000 (im1) / 0
    unsigned mycnt = 0;
    #pragma unroll
    for (int q = 0; q < 4; ++q) {
        int s = t * 4 + q;
        unsigned f = 0;
        if (s < KNMS && kp[s] && ts[s] > 0.f) f = (ti[s] == 0) ? 1u : 0x10000u;
        loc[q] = f;
        mycnt += f;
    }
    scan[t] = mycnt;
    __syncthreads();
    // Hillis-Steele inclusive scan over 256 packed counters
    for (int d = 1; d < 256; d <<= 1) {
        unsigned v = scan[t];
        unsigned add = (t >= d) ? scan[t - d] : 0u;
        __syncthreads();
        scan[t] = v + add;
        __syncthreads();
    }
    unsigned base = (t > 0) ? scan[t - 1] : 0u;   // exclusive prefix
    #pragma unroll
    for (int q = 0; q < 4; ++q) {
        unsigned f = loc[q];
        if (f) {
            int im = (f >> 16) ? 1 : 0;
            unsigned rank = (im ? (base >> 16) : (base & 0xFFFFu));
            if (rank < 100) {
                int s = t * 4 + q;
                int slot = im * 100 + (int)rank;
                for (int d = 0; d < 4; ++d) out[slot * 4 + d] = tb[s * 4 + d];
                out[800 + slot] = ts[s];
                out[1000 + slot] = (float)tc[s];
            }
            base += f;
        }
    }
}

// =====================================================================
extern "C" void kernel_launch(void* const* d_in, const int* in_sizes, int n_in,
                              void* d_out, int out_size, void* d_ws, size_t ws_size,
                              hipStream_t stream) {
    (void)in_sizes; (void)n_in; (void)out_size; (void)ws_size;
    const float* props = (const float*)d_in[0];
    const int*   imidx = (const int*)d_in[1];
    const float* fm0 = (const float*)d_in[2];
    const float* fm1 = (const float*)d_in[3];
    const float* fm2 = (const float*)d_in[4];
    const float* fm3 = (const float*)d_in[5];
    const float* Wfc0 = (const float*)d_in[6];
    const float* bfc0 = (const float*)d_in[7];
    const float* Wfc1 = (const float*)d_in[8];
    const float* bfc1 = (const float*)d_in[9];
    const float* Wcls = (const float*)d_in[10];
    const float* bcls = (const float*)d_in[11];
    const float* Wreg = (const float*)d_in[12];
    const float* breg = (const float*)d_in[13];

    char* p = (char*)d_ws;
    auto alloc = [&](size_t bytes) { char* r = p; p += (bytes + 255) & ~(size_t)255; return r; };

    bf16* fmt0 = (bf16*)alloc((size_t)2 * 40000 * CH * 2);  // 41 MB; re-used as split-K scratch
    bf16* fmt1 = (bf16*)alloc((size_t)2 * 10000 * CH * 2);
    bf16* fmt2 = (bf16*)alloc((size_t)2 * 2500 * CH * 2);
    bf16* fmt3 = (bf16*)alloc((size_t)2 * 625 * CH * 2);
    bf16* Wt0 = (bf16*)alloc((size_t)CLIN * KPAD * 2);
    bf16* Wt1 = (bf16*)alloc((size_t)CLIN * CLIN * 2);
    bf16* Wth = (bf16*)alloc((size_t)NHEAD * CLIN * 2);
    bf16* x0 = (bf16*)alloc((size_t)MPAD * KPAD * 2);
    bf16* x1 = (bf16*)alloc((size_t)MPAD * CLIN * 2);
    bf16* x2 = (bf16*)alloc((size_t)MPAD * CLIN * 2);
    float* heads = (float*)alloc((size_t)MPAD * NHEAD * 4);
    float* boxes = (float*)alloc((size_t)NPROP * NCG * 4 * 4);
    u64* keys = (u64*)alloc((size_t)NPROP * NCG * 8);
    u64* cand = (u64*)alloc((size_t)CAND * 8);
    u64* sorted = (u64*)alloc((size_t)CAND * 8);
    float* tb = (float*)alloc(KNMS * 4 * 4);
    float* toff = (float*)alloc(KNMS * 4 * 4);
    float* ts = (float*)alloc(KNMS * 4);
    int* tc = (int*)alloc(KNMS * 4);
    int* ti = (int*)alloc(KNMS * 4);
    int* cnt = (int*)alloc(256);
    float* Cpart = (float*)fmt0;

    dim3 b328(32, 8, 1);
    fm_transpose<<<dim3(1250, 8, 2), b328, 0, stream>>>(fm0, fmt0, 40000);
    fm_transpose<<<dim3(313, 8, 2), b328, 0, stream>>>(fm1, fmt1, 10000);
    fm_transpose<<<dim3(79, 8, 2), b328, 0, stream>>>(fm2, fmt2, 2500);
    fm_transpose<<<dim3(20, 8, 2), b328, 0, stream>>>(fm3, fmt3, 625);
    wfc0_transpose<<<dim3(50, 8, 32), b328, 0, stream>>>(Wfc0, Wt0);
    w_transpose<<<dim3(32, 32, 1), b328, 0, stream>>>(Wfc1, Wt1, CLIN);
    whead_transpose<<<dim3(32, 16, 1), b328, 0, stream>>>(Wcls, Wreg, Wth);

    roi_align<<<dim3(MPAD), 256, 0, stream>>>(props, imidx, fmt0, fmt1, fmt2, fmt3, x0);

    gemm_nt<<<dim3(8, 8, 8), 256, 0, stream>>>(x0, Wt0, KPAD, 25, Cpart, CLIN, (size_t)MPAD * CLIN);
    reduceK<<<dim3(MPAD * CLIN / 256), 256, 0, stream>>>(Cpart, 8, (size_t)MPAD * CLIN,
        bfc0, CLIN - 1, 1, x1, nullptr);
    gemm_nt<<<dim3(8, 8, 4), 256, 0, stream>>>(x1, Wt1, CLIN, 4, Cpart, CLIN, (size_t)MPAD * CLIN);
    reduceK<<<dim3(MPAD * CLIN / 256), 256, 0, stream>>>(Cpart, 4, (size_t)MPAD * CLIN,
        bfc1, CLIN - 1, 1, x2, nullptr);
    gemm_nt<<<dim3(8, 4, 8), 256, 0, stream>>>(x2, Wth, CLIN, 2, Cpart, NHEAD, (size_t)MPAD * NHEAD);
    reduceK<<<dim3(MPAD * NHEAD / 256), 256, 0, stream>>>(Cpart, 8, (size_t)MPAD * NHEAD,
        nullptr, 0, 0, nullptr, heads);

    hipMemsetAsync(cnt, 0, 4, stream);
    hipMemsetAsync(cand, 0, (size_t)CAND * 8, stream);
    decode<<<dim3(NPROP), 128, 0, stream>>>(heads, bcls, breg, props, imidx, boxes, keys);
    compact<<<dim3((NPROP * NCG + 255) / 256), 256, 0, stream>>>(keys, cand, cnt);
    sortk<<<dim3(1), 1024, 0, stream>>>(cand, sorted, cnt);
    extract<<<dim3(4), 256, 0, stream>>>(sorted, boxes, imidx, tb, toff, ts, tc, ti);
    nms_write<<<dim3(1), 256, 0, stream>>>(toff, tb, ts, tc, ti, (float*)d_out);
}

// Round 4
// 209.534 us; speedup vs baseline: 2.8196x; 1.0805x over previous
//
#include <hip/hip_runtime.h>
#include <hip/hip_bf16.h>
#include <stdint.h>
#include <stddef.h>

typedef __hip_bfloat16 bf16;
typedef short bf16x8s __attribute__((ext_vector_type(8)));
typedef float f32x4 __attribute__((ext_vector_type(4)));
typedef unsigned long long u64;

#define NPROP 1000
#define MPAD  1024
#define NCG   80
#define NCLS  81
#define CH    256
#define KDIM  12544
#define KPAD  12800     // 50 cells * 256
#define CLIN  1024
#define NHEAD 512       // packed heads: [0,81)=cls, [128,448)=reg
#define IMGSZ 800.0f
#define SCORE_THR 0.05f
#define MIN_SIZE 0.01f
#define KNMS 1000
#define CAND 4096
#define DWH_CLAMP_F 4.135166556742356f

__device__ __forceinline__ void async_load16(const void* g, void* l) {
    __builtin_amdgcn_global_load_lds(
        (const __attribute__((address_space(1))) void*)g,
        (__attribute__((address_space(3))) void*)l, 16, 0, 0);
}

// ---------------- fused feature map transpose: NCHW f32 -> NHWC bf16 (all 4 levels) ----------------
__global__ void fm_transpose_all(const float* __restrict__ f0, const float* __restrict__ f1,
                                 const float* __restrict__ f2, const float* __restrict__ f3,
                                 bf16* __restrict__ o0, bf16* __restrict__ o1,
                                 bf16* __restrict__ o2, bf16* __restrict__ o3) {
    __shared__ float tile[32][33];
    int bx = blockIdx.x;
    const float* fm; bf16* fmt; int S;
    if (bx < 1250)      { fm = f0; fmt = o0; S = 40000; }
    else if (bx < 1563) { fm = f1; fmt = o1; S = 10000; bx -= 1250; }
    else if (bx < 1642) { fm = f2; fmt = o2; S = 2500;  bx -= 1563; }
    else                { fm = f3; fmt = o3; S = 625;   bx -= 1642; }
    int b = blockIdx.z;
    int sBase = bx * 32;
    int cBase = blockIdx.y * 32;
    int tx = threadIdx.x, ty = threadIdx.y;
#pragma unroll
    for (int i = 0; i < 4; ++i) {
        int c = cBase + ty + i * 8;
        int s = sBase + tx;
        float v = 0.f;
        if (s < S) v = fm[((size_t)(b * CH + c)) * S + s];
        tile[ty + i * 8][tx] = v;
    }
    __syncthreads();
#pragma unroll
    for (int i = 0; i < 4; ++i) {
        int s = sBase + ty + i * 8;
        int c = cBase + tx;
        if (s < S) fmt[((size_t)b * S + s) * CH + c] = __float2bfloat16(tile[tx][ty + i * 8]);
    }
}

// --------- W_fc0 (12544x1024) -> Wt0 (1024 x KPAD), k' = cell*256 + c, pad cell 49 = 0 ----
__global__ void wfc0_transpose(const float* __restrict__ W, bf16* __restrict__ Wt) {
    __shared__ float tile[32][33];
    int cell = blockIdx.x;          // 0..49 (49 = zero pad)
    int cBase = blockIdx.y * 32;
    int nBase = blockIdx.z * 32;
    int tx = threadIdx.x, ty = threadIdx.y;
#pragma unroll
    for (int i = 0; i < 4; ++i) {
        int c = cBase + ty + i * 8;
        float v = 0.f;
        if (cell < 49) v = W[(size_t)(c * 49 + cell) * CLIN + nBase + tx];
        tile[ty + i * 8][tx] = v;
    }
    __syncthreads();
#pragma unroll
    for (int i = 0; i < 4; ++i) {
        int n = nBase + ty + i * 8;
        Wt[(size_t)n * KPAD + cell * CH + cBase + tx] = __float2bfloat16(tile[tx][ty + i * 8]);
    }
}

// --------- W (1024 x ncols) -> Wt (npad x 1024) bf16 ----------
__global__ void w_transpose(const float* __restrict__ W, bf16* __restrict__ Wt, int ncols) {
    __shared__ float tile[32][33];
    int kBase = blockIdx.x * 32;
    int nBase = blockIdx.y * 32;
    int tx = threadIdx.x, ty = threadIdx.y;
#pragma unroll
    for (int i = 0; i < 4; ++i) {
        int k = kBase + ty + i * 8;
        int n = nBase + tx;
        float v = 0.f;
        if (n < ncols) v = W[(size_t)k * ncols + n];
        tile[ty + i * 8][tx] = v;
    }
    __syncthreads();
#pragma unroll
    for (int i = 0; i < 4; ++i) {
        int n = nBase + ty + i * 8;
        Wt[(size_t)n * CLIN + kBase + tx] = __float2bfloat16(tile[tx][ty + i * 8]);
    }
}

// --------- packed head weights: Wth[j][k], j<81 = Wcls col j, 128<=j<448 = Wreg col j-128 ----
__global__ void whead_transpose(const float* __restrict__ Wc, const float* __restrict__ Wr,
                                bf16* __restrict__ Wt) {
    __shared__ float tile[32][33];
    int kBase = blockIdx.x * 32;
    int jBase = blockIdx.y * 32;
    int tx = threadIdx.x, ty = threadIdx.y;
#pragma unroll
    for (int i = 0; i < 4; ++i) {
        int k = kBase + ty + i * 8;
        int j = jBase + tx;
        float v = 0.f;
        if (j < NCLS) v = Wc[(size_t)k * NCLS + j];
        else if (j >= 128 && j < 448) v = Wr[(size_t)k * (NCG * 4) + (j - 128)];
        tile[ty + i * 8][tx] = v;
    }
    __syncthreads();
#pragma unroll
    for (int i = 0; i < 4; ++i) {
        int j = jBase + ty + i * 8;
        Wt[(size_t)j * CLIN + kBase + tx] = __float2bfloat16(tile[tx][ty + i * 8]);
    }
}

// ------- RoI align: block = proposal; thread = (cell-half, 2-channel group); u32 loads -------
__global__ __launch_bounds__(256) void roi_align(
    const float* __restrict__ props, const int* __restrict__ imidx,
    const bf16* __restrict__ f0, const bf16* __restrict__ f1,
    const bf16* __restrict__ f2, const bf16* __restrict__ f3,
    bf16* __restrict__ x0) {
    int n = blockIdx.x;
    int t = threadIdx.x;
    unsigned* outp = (unsigned*)(x0 + (size_t)n * KPAD);
    if (n >= NPROP) {   // zero pad rows: 6400 u32 per row
        for (int i = t; i < KPAD / 2; i += 256) outp[i] = 0u;
        return;
    }
    __shared__ int4  soff[196];   // u32-unit offsets of 4 corners
    __shared__ float4 swt[196];   // 4 corner weights (incl. 0.25 avg factor)
    float px1 = props[n * 4 + 0], py1 = props[n * 4 + 1];
    float px2 = props[n * 4 + 2], py2 = props[n * 4 + 3];
    float w = px2 - px1, h = py2 - py1;
    float lvlf = floorf(4.0f + log2f(sqrtf(fmaxf(w * h, 1e-6f)) / 224.0f));
    int lvl = (int)fminf(fmaxf(lvlf, 2.0f), 5.0f) - 2;
    const bf16* fmt; int H, Wd; float inv;
    if (lvl == 0)      { fmt = f0; H = 200; Wd = 200; inv = 0.25f; }
    else if (lvl == 1) { fmt = f1; H = 100; Wd = 100; inv = 0.125f; }
    else if (lvl == 2) { fmt = f2; H = 50;  Wd = 50;  inv = 0.0625f; }
    else               { fmt = f3; H = 25;  Wd = 25;  inv = 0.03125f; }
    const unsigned* basep = (const unsigned*)(fmt + (size_t)imidx[n] * H * Wd * CH);
    if (t < 196) {
        int py = t / 14, px = t - py * 14;
        float x1s = px1 * inv, y1s = py1 * inv;
        float dxs = w * inv, dys = h * inv;
        float fx = ((float)px + 0.5f) * (1.0f / 14.0f);
        float fy = ((float)py + 0.5f) * (1.0f / 14.0f);
        float gx = fminf(fmaxf(x1s + fx * dxs, 0.f), (float)(Wd - 1));
        float gy = fminf(fmaxf(y1s + fy * dys, 0.f), (float)(H - 1));
        float x0f = floorf(gx), y0f = floorf(gy);
        int x0i = (int)x0f, y0i = (int)y0f;
        int x1i = min(x0i + 1, Wd - 1), y1i = min(y0i + 1, H - 1);
        float lx = gx - x0f, ly = gy - y0f;
        int4 so;
        so.x = (y0i * Wd + x0i) * (CH / 2);
        so.y = (y0i * Wd + x1i) * (CH / 2);
        so.z = (y1i * Wd + x0i) * (CH / 2);
        so.w = (y1i * Wd + x1i) * (CH / 2);
        soff[t] = so;
        float4 wt;
        wt.x = 0.25f * (1.f - ly) * (1.f - lx);
        wt.y = 0.25f * (1.f - ly) * lx;
        wt.z = 0.25f * ly * (1.f - lx);
        wt.w = 0.25f * ly * lx;
        swt[t] = wt;
    }
    __syncthreads();
    int half = t >> 7;           // 0: cells 0..24, 1: cells 25..48
    int tc = t & 127;            // u32 channel group (2 bf16 channels)
    int c0 = half ? 25 : 0;
    int cN = half ? 24 : 25;
    for (int k = 0; k < cN; ++k) {
        int cell = c0 + k;
        int ci = cell / 7, cj = cell - ci * 7;
        float accL = 0.f, accH = 0.f;
#pragma unroll
        for (int sy = 0; sy < 2; ++sy) {
#pragma unroll
            for (int sx = 0; sx < 2; ++sx) {
                int p = (ci * 2 + sy) * 14 + (cj * 2 + sx);
                int4 so = soff[p];
                float4 wt = swt[p];
                unsigned u;
                u = basep[so.x + tc];
                accL += wt.x * __uint_as_float(u << 16);
                accH += wt.x * __uint_as_float(u & 0xFFFF0000u);
                u = basep[so.y + tc];
                accL += wt.y * __uint_as_float(u << 16);
                accH += wt.y * __uint_as_float(u & 0xFFFF0000u);
                u = basep[so.z + tc];
                accL += wt.z * __uint_as_float(u << 16);
                accH += wt.z * __uint_as_float(u & 0xFFFF0000u);
                u = basep[so.w + tc];
                accL += wt.w * __uint_as_float(u << 16);
                accH += wt.w * __uint_as_float(u & 0xFFFF0000u);
            }
        }
        unsigned lo = (unsigned)__builtin_bit_cast(unsigned short, __float2bfloat16(accL));
        unsigned hi = (unsigned)__builtin_bit_cast(unsigned short, __float2bfloat16(accH));
        outp[cell * 128 + tc] = lo | (hi << 16);
    }
    if (half == 0) outp[49 * 128 + tc] = 0u;   // zero pad cell
}

// -------- bf16 MFMA NT-GEMM, m97 structure: gload_lds + dbuf + 2-phase prefetch ---------
#define BM 128
#define BK 64
__global__ __launch_bounds__(256) void gemm_nt(
    const bf16* __restrict__ A, const bf16* __restrict__ B,
    int lda, int kSteps, float* __restrict__ part, int ldc, size_t zStride) {
    __shared__ short Al[2][BM * BK];
    __shared__ short Bl[2][BM * BK];
    int tid = threadIdx.x;
    int bm = blockIdx.x * BM;
    int bn = blockIdx.y * BM;
    int z = blockIdx.z;
    int wave = tid >> 6, lane = tid & 63;
    int wm = (wave >> 1) * 64, wn = (wave & 1) * 64;
    int lr = lane & 15, lk = lane >> 4;
    int rowS = wave * 8 + (lane >> 3);
    int colS = (lane & 7) * 8;

    f32x4 acc[4][4];
#pragma unroll
    for (int i = 0; i < 4; ++i)
#pragma unroll
        for (int j = 0; j < 4; ++j) acc[i][j] = (f32x4){0.f, 0.f, 0.f, 0.f};

    const bf16* gA = A + (size_t)(bm + rowS) * lda + colS + (size_t)z * kSteps * BK;
    const bf16* gB = B + (size_t)(bn + rowS) * lda + colS + (size_t)z * kSteps * BK;

    auto STAGE = [&](int buf, int kt) {
        size_t ko = (size_t)kt * BK;
#pragma unroll
        for (int it = 0; it < 4; ++it) {
            async_load16(gA + ko + (size_t)it * 32 * lda, &Al[buf][(it * 32 + rowS) * BK + colS]);
            async_load16(gB + ko + (size_t)it * 32 * lda, &Bl[buf][(it * 32 + rowS) * BK + colS]);
        }
    };
    auto COMPUTE = [&](int buf) {
#pragma unroll
        for (int ks = 0; ks < 2; ++ks) {
            bf16x8s af[4], bfr[4];
#pragma unroll
            for (int i = 0; i < 4; ++i)
                af[i] = *(const bf16x8s*)&Al[buf][(wm + i * 16 + lr) * BK + ks * 32 + lk * 8];
#pragma unroll
            for (int j = 0; j < 4; ++j)
                bfr[j] = *(const bf16x8s*)&Bl[buf][(wn + j * 16 + lr) * BK + ks * 32 + lk * 8];
#pragma unroll
            for (int i = 0; i < 4; ++i)
#pragma unroll
                for (int j = 0; j < 4; ++j)
                    acc[i][j] = __builtin_amdgcn_mfma_f32_16x16x32_bf16(af[i], bfr[j], acc[i][j], 0, 0, 0);
        }
    };

    int cur = 0;
    STAGE(0, 0);
    asm volatile("s_waitcnt vmcnt(0)" ::: "memory");
    __syncthreads();
    for (int kt = 0; kt < kSteps; ++kt) {
        if (kt + 1 < kSteps) STAGE(cur ^ 1, kt + 1);
        COMPUTE(cur);
        asm volatile("s_waitcnt vmcnt(0)" ::: "memory");
        __syncthreads();
        cur ^= 1;
    }
    float* outp = part + (size_t)z * zStride;
#pragma unroll
    for (int i = 0; i < 4; ++i) {
        int mbase = bm + wm + i * 16 + lk * 4;
#pragma unroll
        for (int j = 0; j < 4; ++j) {
            int ncol = bn + wn + j * 16 + lr;
#pragma unroll
            for (int r = 0; r < 4; ++r)
                outp[(size_t)(mbase + r) * ldc + ncol] = acc[i][j][r];
        }
    }
}

// ---------------- split-K reduce (+bias, +relu) -> bf16 or f32 ----------------
__global__ void reduceK(const float* __restrict__ part, int nsplit, size_t zStride,
                        const float* __restrict__ bias, int colMask, int relu,
                        bf16* __restrict__ outB, float* __restrict__ outF) {
    int idx = blockIdx.x * 256 + threadIdx.x;
    float v = bias ? bias[idx & colMask] : 0.f;
    for (int s = 0; s < nsplit; ++s) v += part[(size_t)s * zStride + idx];
    if (relu) v = fmaxf(v, 0.f);
    if (outB) outB[idx] = __float2bfloat16(v);
    else outF[idx] = v;
}

// ------------ softmax + box decode + direct candidate push (compact fused) ------------
__global__ __launch_bounds__(128) void decode(
    const float* __restrict__ heads,
    const float* __restrict__ bcls, const float* __restrict__ breg,
    const float* __restrict__ props, const int* __restrict__ imidx,
    float* __restrict__ boxes, u64* __restrict__ cand, int* __restrict__ cnt) {
    __shared__ float red[128];
    int n = blockIdx.x, t = threadIdx.x;
    float l = (t < NCLS) ? heads[(size_t)n * NHEAD + t] + bcls[t] : -1e30f;
    red[t] = l; __syncthreads();
    for (int s = 64; s > 0; s >>= 1) { if (t < s) red[t] = fmaxf(red[t], red[t + s]); __syncthreads(); }
    float mx = red[0]; __syncthreads();
    float e = (t < NCLS) ? expf(l - mx) : 0.f;
    red[t] = e; __syncthreads();
    for (int s = 64; s > 0; s >>= 1) { if (t < s) red[t] += red[t + s]; __syncthreads(); }
    float denom = red[0];
    if (t >= NCG) return;
    float score = e / denom;
    float px1 = props[n * 4 + 0], py1 = props[n * 4 + 1];
    float px2 = props[n * 4 + 2], py2 = props[n * 4 + 3];
    float pw = px2 - px1, ph = py2 - py1;
    float pcx = px1 + 0.5f * pw, pcy = py1 + 0.5f * ph;
    const float* r4 = heads + (size_t)n * NHEAD + 128 + t * 4;
    float dx = (r4[0] + breg[t * 4 + 0]) * 0.1f;
    float dy = (r4[1] + breg[t * 4 + 1]) * 0.1f;
    float dw = fminf((r4[2] + breg[t * 4 + 2]) * 0.2f, DWH_CLAMP_F);
    float dh = fminf((r4[3] + breg[t * 4 + 3]) * 0.2f, DWH_CLAMP_F);
    float cx = pcx + dx * pw, cy = pcy + dy * ph;
    float bw = pw * expf(dw), bh = ph * expf(dh);
    float x1 = fminf(fmaxf(cx - 0.5f * bw, 0.f), IMGSZ);
    float y1 = fminf(fmaxf(cy - 0.5f * bh, 0.f), IMGSZ);
    float x2 = fminf(fmaxf(cx + 0.5f * bw, 0.f), IMGSZ);
    float y2 = fminf(fmaxf(cy + 0.5f * bh, 0.f), IMGSZ);
    int idx = n * NCG + t;
    float* bo = boxes + (size_t)idx * 4;
    bo[0] = x1; bo[1] = y1; bo[2] = x2; bo[3] = y2;
    bool valid = (score > SCORE_THR) && ((x2 - x1) >= MIN_SIZE) && ((y2 - y1) >= MIN_SIZE);
    if (valid) {
        u64 key = ((u64)__float_as_uint(score) << 17) | (u64)(0x1FFFFu - (unsigned)idx);
        int p = atomicAdd(cnt, 1);
        if (p < CAND) cand[p] = key;
    }
}

// -------- bitonic descending sort (dynamic size) + top-1000 attribute extract, one block --------
__global__ __launch_bounds__(1024) void sort_extract(
    const u64* __restrict__ cand, const int* __restrict__ cntp,
    const float* __restrict__ boxes, const int* __restrict__ imidx,
    float* __restrict__ tb, float* __restrict__ toff,
    float* __restrict__ ts, int* __restrict__ tc, int* __restrict__ ti) {
    __shared__ u64 s[CAND];
    int t = threadIdx.x;
    int n = min(*cntp, CAND);
    if (n > 0) {
        int NS = (n <= 1024) ? 1024 : ((n <= 2048) ? 2048 : 4096);
        int E = NS >> 10;
        for (int p = 0; p < E; ++p) { int i = t + p * 1024; s[i] = (i < n) ? cand[i] : 0ull; }
        __syncthreads();
        for (int k = 2; k <= NS; k <<= 1) {
            for (int j = k >> 1; j > 0; j >>= 1) {
                for (int p = 0; p < E; ++p) {
                    int i = t + p * 1024;
                    int l = i ^ j;
                    if (l > i && l < NS) {
                        u64 a = s[i], b = s[l];
                        bool desc = ((i & k) == 0);
                        if (desc ? (a < b) : (a > b)) { s[i] = b; s[l] = a; }
                    }
                }
                __syncthreads();
            }
        }
    }
    if (t >= KNMS) return;
    u64 key = (n > 0) ? s[t] : 0ull;
    if (key == 0ull) {
        ts[t] = -1.f; tc[t] = -1; ti[t] = -1;
        for (int d = 0; d < 4; ++d) { tb[t * 4 + d] = 0.f; toff[t * 4 + d] = 0.f; }
        return;
    }
    unsigned idx = 0x1FFFFu - (unsigned)(key & 0x1FFFFull);
    float score = __uint_as_float((unsigned)(key >> 17));
    int nn = idx / NCG, c = idx - nn * NCG;
    int im = imidx[nn];
    float off = (float)(im * NCG + c) * 1000.0f;
    for (int d = 0; d < 4; ++d) {
        float v = boxes[(size_t)idx * 4 + d];
        tb[t * 4 + d] = v;
        toff[t * 4 + d] = v + off;
    }
    ts[t] = score; tc[t] = c; ti[t] = im;
}

// ------------- fused greedy NMS + parallel per-image top-100 writeout -------------
__global__ __launch_bounds__(256) void nms_write(
    const float* __restrict__ toff, const float* __restrict__ tb,
    const float* __restrict__ ts, const int* __restrict__ tc, const int* __restrict__ ti,
    float* __restrict__ out) {
    __shared__ float4 bx[KNMS];
    __shared__ int kp[KNMS];
    __shared__ int Vsh;
    __shared__ unsigned scan[256];
    int t = threadIdx.x;
    if (t == 0) Vsh = KNMS;
    __syncthreads();
    for (int s = t; s < KNMS; s += 256) {
        bx[s] = ((const float4*)toff)[s];
        bool ok = ts[s] > 0.f;
        kp[s] = ok ? 1 : 0;
        if (!ok) atomicMin(&Vsh, s);
    }
    __syncthreads();
    int V = Vsh;   // valid entries form a prefix (sorted descending)
    for (int i = 0; i < V; ++i) {
        if (kp[i]) {
            float4 bi = bx[i];
            float ai = (bi.z - bi.x) * (bi.w - bi.y);
            for (int j2 = i + 1 + t; j2 < V; j2 += 256) {
                if (!kp[j2]) continue;
                float4 bj = bx[j2];
                float xx1 = fmaxf(bi.x, bj.x), yy1 = fmaxf(bi.y, bj.y);
                float xx2 = fminf(bi.z, bj.z), yy2 = fminf(bi.w, bj.w);
                float iw = fmaxf(xx2 - xx1, 0.f), ih = fmaxf(yy2 - yy1, 0.f);
                float inter = iw * ih;
                float aj = (bj.z - bj.x) * (bj.w - bj.y);
                float iou = inter / fmaxf(ai + aj - inter, 1e-9f);
                if (iou > 0.5f) kp[j2] = 0;
            }
        }
        __syncthreads();
    }
    for (int r = t; r < 200; r += 256) {
        for (int d = 0; d < 4; ++d) out[r * 4 + d] = 0.f;
        out[800 + r] = 0.f;
        out[1000 + r] = -1.0f;
    }
    unsigned loc[4];
    unsigned mycnt = 0;
    #pragma unroll
    for (int q = 0; q < 4; ++q) {
        int s = t * 4 + q;
        unsigned f = 0;
        if (s < KNMS && kp[s] && ts[s] > 0.f) f = (ti[s] == 0) ? 1u : 0x10000u;
        loc[q] = f;
        mycnt += f;
    }
    scan[t] = mycnt;
    __syncthreads();
    for (int d = 1; d < 256; d <<= 1) {
        unsigned v = scan[t];
        unsigned add = (t >= d) ? scan[t - d] : 0u;
        __syncthreads();
        scan[t] = v + add;
        __syncthreads();
    }
    unsigned base = (t > 0) ? scan[t - 1] : 0u;
    #pragma unroll
    for (int q = 0; q < 4; ++q) {
        unsigned f = loc[q];
        if (f) {
            int im = (f >> 16) ? 1 : 0;
            unsigned rank = (im ? (base >> 16) : (base & 0xFFFFu));
            if (rank < 100) {
                int s = t * 4 + q;
                int slot = im * 100 + (int)rank;
                for (int d = 0; d < 4; ++d) out[slot * 4 + d] = tb[s * 4 + d];
                out[800 + slot] = ts[s];
                out[1000 + slot] = (float)tc[s];
            }
            base += f;
        }
    }
}

// =====================================================================
extern "C" void kernel_launch(void* const* d_in, const int* in_sizes, int n_in,
                              void* d_out, int out_size, void* d_ws, size_t ws_size,
                              hipStream_t stream) {
    (void)in_sizes; (void)n_in; (void)out_size; (void)ws_size;
    const float* props = (const float*)d_in[0];
    const int*   imidx = (const int*)d_in[1];
    const float* fm0 = (const float*)d_in[2];
    const float* fm1 = (const float*)d_in[3];
    const float* fm2 = (const float*)d_in[4];
    const float* fm3 = (const float*)d_in[5];
    const float* Wfc0 = (const float*)d_in[6];
    const float* bfc0 = (const float*)d_in[7];
    const float* Wfc1 = (const float*)d_in[8];
    const float* bfc1 = (const float*)d_in[9];
    const float* Wcls = (const float*)d_in[10];
    const float* bcls = (const float*)d_in[11];
    const float* Wreg = (const float*)d_in[12];
    const float* breg = (const float*)d_in[13];

    char* p = (char*)d_ws;
    auto alloc = [&](size_t bytes) { char* r = p; p += (bytes + 255) & ~(size_t)255; return r; };

    bf16* fmt0 = (bf16*)alloc((size_t)2 * 40000 * CH * 2);  // 41 MB; re-used as split-K scratch
    bf16* fmt1 = (bf16*)alloc((size_t)2 * 10000 * CH * 2);
    bf16* fmt2 = (bf16*)alloc((size_t)2 * 2500 * CH * 2);
    bf16* fmt3 = (bf16*)alloc((size_t)2 * 625 * CH * 2);
    bf16* Wt0 = (bf16*)alloc((size_t)CLIN * KPAD * 2);
    bf16* Wt1 = (bf16*)alloc((size_t)CLIN * CLIN * 2);
    bf16* Wth = (bf16*)alloc((size_t)NHEAD * CLIN * 2);
    bf16* x0 = (bf16*)alloc((size_t)MPAD * KPAD * 2);
    bf16* x1 = (bf16*)alloc((size_t)MPAD * CLIN * 2);
    bf16* x2 = (bf16*)alloc((size_t)MPAD * CLIN * 2);
    float* heads = (float*)alloc((size_t)MPAD * NHEAD * 4);
    float* boxes = (float*)alloc((size_t)NPROP * NCG * 4 * 4);
    u64* cand = (u64*)alloc((size_t)CAND * 8);
    float* tb = (float*)alloc(KNMS * 4 * 4);
    float* toff = (float*)alloc(KNMS * 4 * 4);
    float* ts = (float*)alloc(KNMS * 4);
    int* tc = (int*)alloc(KNMS * 4);
    int* ti = (int*)alloc(KNMS * 4);
    int* cnt = (int*)alloc(256);
    float* Cpart = (float*)fmt0;

    dim3 b328(32, 8, 1);
    fm_transpose_all<<<dim3(1662, 8, 2), b328, 0, stream>>>(fm0, fm1, fm2, fm3,
                                                            fmt0, fmt1, fmt2, fmt3);
    wfc0_transpose<<<dim3(50, 8, 32), b328, 0, stream>>>(Wfc0, Wt0);
    w_transpose<<<dim3(32, 32, 1), b328, 0, stream>>>(Wfc1, Wt1, CLIN);
    whead_transpose<<<dim3(32, 16, 1), b328, 0, stream>>>(Wcls, Wreg, Wth);

    roi_align<<<dim3(MPAD), 256, 0, stream>>>(props, imidx, fmt0, fmt1, fmt2, fmt3, x0);

    gemm_nt<<<dim3(8, 8, 8), 256, 0, stream>>>(x0, Wt0, KPAD, 25, Cpart, CLIN, (size_t)MPAD * CLIN);
    reduceK<<<dim3(MPAD * CLIN / 256), 256, 0, stream>>>(Cpart, 8, (size_t)MPAD * CLIN,
        bfc0, CLIN - 1, 1, x1, nullptr);
    gemm_nt<<<dim3(8, 8, 4), 256, 0, stream>>>(x1, Wt1, CLIN, 4, Cpart, CLIN, (size_t)MPAD * CLIN);
    reduceK<<<dim3(MPAD * CLIN / 256), 256, 0, stream>>>(Cpart, 4, (size_t)MPAD * CLIN,
        bfc1, CLIN - 1, 1, x2, nullptr);
    gemm_nt<<<dim3(8, 4, 8), 256, 0, stream>>>(x2, Wth, CLIN, 2, Cpart, NHEAD, (size_t)MPAD * NHEAD);
    reduceK<<<dim3(MPAD * NHEAD / 256), 256, 0, stream>>>(Cpart, 8, (size_t)MPAD * NHEAD,
        nullptr, 0, 0, nullptr, heads);

    hipMemsetAsync(cnt, 0, 4, stream);
    decode<<<dim3(NPROP), 128, 0, stream>>>(heads, bcls, breg, props, imidx, boxes, cand, cnt);
    sort_extract<<<dim3(1), 1024, 0, stream>>>(cand, cnt, boxes, imidx, tb, toff, ts, tc, ti);
    nms_write<<<dim3(1), 256, 0, stream>>>(toff, tb, ts, tc, ti, (float*)d_out);
}

// Round 5
// 201.414 us; speedup vs baseline: 2.9332x; 1.0403x over previous
//
#include <hip/hip_runtime.h>
#include <hip/hip_bf16.h>
#include <stdint.h>
#include <stddef.h>

typedef __hip_bfloat16 bf16;
typedef short bf16x8s __attribute__((ext_vector_type(8)));
typedef float f32x4 __attribute__((ext_vector_type(4)));
typedef unsigned long long u64;

#define NPROP 1000
#define MPAD  1024
#define NCG   80
#define NCLS  81
#define CH    256
#define KDIM  12544
#define KPAD  12800     // 50 cells * 256
#define CLIN  1024
#define NHEAD 512       // packed heads: [0,81)=cls, [128,448)=reg
#define IMGSZ 800.0f
#define SCORE_THR 0.05f
#define MIN_SIZE 0.01f
#define KNMS 1000
#define CAND 4096
#define DWH_CLAMP_F 4.135166556742356f

__device__ __forceinline__ void async_load16(const void* g, void* l) {
    __builtin_amdgcn_global_load_lds(
        (const __attribute__((address_space(1))) void*)g,
        (__attribute__((address_space(3))) void*)l, 16, 0, 0);
}

// ---------------- fused feature map transpose: NCHW f32 -> NHWC bf16 (all 4 levels) ----------------
__global__ void fm_transpose_all(const float* __restrict__ f0, const float* __restrict__ f1,
                                 const float* __restrict__ f2, const float* __restrict__ f3,
                                 bf16* __restrict__ o0, bf16* __restrict__ o1,
                                 bf16* __restrict__ o2, bf16* __restrict__ o3) {
    __shared__ float tile[32][33];
    int bx = blockIdx.x;
    const float* fm; bf16* fmt; int S;
    if (bx < 1250)      { fm = f0; fmt = o0; S = 40000; }
    else if (bx < 1563) { fm = f1; fmt = o1; S = 10000; bx -= 1250; }
    else if (bx < 1642) { fm = f2; fmt = o2; S = 2500;  bx -= 1563; }
    else                { fm = f3; fmt = o3; S = 625;   bx -= 1642; }
    int b = blockIdx.z;
    int sBase = bx * 32;
    int cBase = blockIdx.y * 32;
    int tx = threadIdx.x, ty = threadIdx.y;
#pragma unroll
    for (int i = 0; i < 4; ++i) {
        int c = cBase + ty + i * 8;
        int s = sBase + tx;
        float v = 0.f;
        if (s < S) v = fm[((size_t)(b * CH + c)) * S + s];
        tile[ty + i * 8][tx] = v;
    }
    __syncthreads();
#pragma unroll
    for (int i = 0; i < 4; ++i) {
        int s = sBase + ty + i * 8;
        int c = cBase + tx;
        if (s < S) fmt[((size_t)b * S + s) * CH + c] = __float2bfloat16(tile[tx][ty + i * 8]);
    }
}

// --------- W_fc0 (12544x1024) -> Wt0 (1024 x KPAD), k' = cell*256 + c, pad cell 49 = 0 ----
__global__ void wfc0_transpose(const float* __restrict__ W, bf16* __restrict__ Wt) {
    __shared__ float tile[32][33];
    int cell = blockIdx.x;          // 0..49 (49 = zero pad)
    int cBase = blockIdx.y * 32;
    int nBase = blockIdx.z * 32;
    int tx = threadIdx.x, ty = threadIdx.y;
#pragma unroll
    for (int i = 0; i < 4; ++i) {
        int c = cBase + ty + i * 8;
        float v = 0.f;
        if (cell < 49) v = W[(size_t)(c * 49 + cell) * CLIN + nBase + tx];
        tile[ty + i * 8][tx] = v;
    }
    __syncthreads();
#pragma unroll
    for (int i = 0; i < 4; ++i) {
        int n = nBase + ty + i * 8;
        Wt[(size_t)n * KPAD + cell * CH + cBase + tx] = __float2bfloat16(tile[tx][ty + i * 8]);
    }
}

// --------- W (1024 x ncols) -> Wt (npad x 1024) bf16 ----------
__global__ void w_transpose(const float* __restrict__ W, bf16* __restrict__ Wt, int ncols) {
    __shared__ float tile[32][33];
    int kBase = blockIdx.x * 32;
    int nBase = blockIdx.y * 32;
    int tx = threadIdx.x, ty = threadIdx.y;
#pragma unroll
    for (int i = 0; i < 4; ++i) {
        int k = kBase + ty + i * 8;
        int n = nBase + tx;
        float v = 0.f;
        if (n < ncols) v = W[(size_t)k * ncols + n];
        tile[ty + i * 8][tx] = v;
    }
    __syncthreads();
#pragma unroll
    for (int i = 0; i < 4; ++i) {
        int n = nBase + ty + i * 8;
        Wt[(size_t)n * CLIN + kBase + tx] = __float2bfloat16(tile[tx][ty + i * 8]);
    }
}

// --------- packed head weights: Wth[j][k], j<81 = Wcls col j, 128<=j<448 = Wreg col j-128 ----
__global__ void whead_transpose(const float* __restrict__ Wc, const float* __restrict__ Wr,
                                bf16* __restrict__ Wt) {
    __shared__ float tile[32][33];
    int kBase = blockIdx.x * 32;
    int jBase = blockIdx.y * 32;
    int tx = threadIdx.x, ty = threadIdx.y;
#pragma unroll
    for (int i = 0; i < 4; ++i) {
        int k = kBase + ty + i * 8;
        int j = jBase + tx;
        float v = 0.f;
        if (j < NCLS) v = Wc[(size_t)k * NCLS + j];
        else if (j >= 128 && j < 448) v = Wr[(size_t)k * (NCG * 4) + (j - 128)];
        tile[ty + i * 8][tx] = v;
    }
    __syncthreads();
#pragma unroll
    for (int i = 0; i < 4; ++i) {
        int j = jBase + ty + i * 8;
        Wt[(size_t)j * CLIN + kBase + tx] = __float2bfloat16(tile[tx][ty + i * 8]);
    }
}

// ------- RoI align: block = proposal; thread = (cell-half, 2-channel group); u32 loads -------
__global__ __launch_bounds__(256) void roi_align(
    const float* __restrict__ props, const int* __restrict__ imidx,
    const bf16* __restrict__ f0, const bf16* __restrict__ f1,
    const bf16* __restrict__ f2, const bf16* __restrict__ f3,
    bf16* __restrict__ x0) {
    int n = blockIdx.x;
    int t = threadIdx.x;
    unsigned* outp = (unsigned*)(x0 + (size_t)n * KPAD);
    if (n >= NPROP) {   // zero pad rows: 6400 u32 per row
        for (int i = t; i < KPAD / 2; i += 256) outp[i] = 0u;
        return;
    }
    __shared__ int4  soff[196];   // u32-unit offsets of 4 corners
    __shared__ float4 swt[196];   // 4 corner weights (incl. 0.25 avg factor)
    float px1 = props[n * 4 + 0], py1 = props[n * 4 + 1];
    float px2 = props[n * 4 + 2], py2 = props[n * 4 + 3];
    float w = px2 - px1, h = py2 - py1;
    float lvlf = floorf(4.0f + log2f(sqrtf(fmaxf(w * h, 1e-6f)) / 224.0f));
    int lvl = (int)fminf(fmaxf(lvlf, 2.0f), 5.0f) - 2;
    const bf16* fmt; int H, Wd; float inv;
    if (lvl == 0)      { fmt = f0; H = 200; Wd = 200; inv = 0.25f; }
    else if (lvl == 1) { fmt = f1; H = 100; Wd = 100; inv = 0.125f; }
    else if (lvl == 2) { fmt = f2; H = 50;  Wd = 50;  inv = 0.0625f; }
    else               { fmt = f3; H = 25;  Wd = 25;  inv = 0.03125f; }
    const unsigned* basep = (const unsigned*)(fmt + (size_t)imidx[n] * H * Wd * CH);
    if (t < 196) {
        int py = t / 14, px = t - py * 14;
        float x1s = px1 * inv, y1s = py1 * inv;
        float dxs = w * inv, dys = h * inv;
        float fx = ((float)px + 0.5f) * (1.0f / 14.0f);
        float fy = ((float)py + 0.5f) * (1.0f / 14.0f);
        float gx = fminf(fmaxf(x1s + fx * dxs, 0.f), (float)(Wd - 1));
        float gy = fminf(fmaxf(y1s + fy * dys, 0.f), (float)(H - 1));
        float x0f = floorf(gx), y0f = floorf(gy);
        int x0i = (int)x0f, y0i = (int)y0f;
        int x1i = min(x0i + 1, Wd - 1), y1i = min(y0i + 1, H - 1);
        float lx = gx - x0f, ly = gy - y0f;
        int4 so;
        so.x = (y0i * Wd + x0i) * (CH / 2);
        so.y = (y0i * Wd + x1i) * (CH / 2);
        so.z = (y1i * Wd + x0i) * (CH / 2);
        so.w = (y1i * Wd + x1i) * (CH / 2);
        soff[t] = so;
        float4 wt;
        wt.x = 0.25f * (1.f - ly) * (1.f - lx);
        wt.y = 0.25f * (1.f - ly) * lx;
        wt.z = 0.25f * ly * (1.f - lx);
        wt.w = 0.25f * ly * lx;
        swt[t] = wt;
    }
    __syncthreads();
    int half = t >> 7;           // 0: cells 0..24, 1: cells 25..48
    int tc = t & 127;            // u32 channel group (2 bf16 channels)
    int c0 = half ? 25 : 0;
    int cN = half ? 24 : 25;
    for (int k = 0; k < cN; ++k) {
        int cell = c0 + k;
        int ci = cell / 7, cj = cell - ci * 7;
        float accL = 0.f, accH = 0.f;
#pragma unroll
        for (int sy = 0; sy < 2; ++sy) {
#pragma unroll
            for (int sx = 0; sx < 2; ++sx) {
                int p = (ci * 2 + sy) * 14 + (cj * 2 + sx);
                int4 so = soff[p];
                float4 wt = swt[p];
                unsigned u;
                u = basep[so.x + tc];
                accL += wt.x * __uint_as_float(u << 16);
                accH += wt.x * __uint_as_float(u & 0xFFFF0000u);
                u = basep[so.y + tc];
                accL += wt.y * __uint_as_float(u << 16);
                accH += wt.y * __uint_as_float(u & 0xFFFF0000u);
                u = basep[so.z + tc];
                accL += wt.z * __uint_as_float(u << 16);
                accH += wt.z * __uint_as_float(u & 0xFFFF0000u);
                u = basep[so.w + tc];
                accL += wt.w * __uint_as_float(u << 16);
                accH += wt.w * __uint_as_float(u & 0xFFFF0000u);
            }
        }
        unsigned lo = (unsigned)__builtin_bit_cast(unsigned short, __float2bfloat16(accL));
        unsigned hi = (unsigned)__builtin_bit_cast(unsigned short, __float2bfloat16(accH));
        outp[cell * 128 + tc] = lo | (hi << 16);
    }
    if (half == 0) outp[49 * 128 + tc] = 0u;   // zero pad cell
}

// -------- bf16 MFMA NT-GEMM: gload_lds + dbuf + 2-phase prefetch + XOR-swizzled LDS ---------
// Swizzle (rule #21, both-sides): LDS linear dest; SOURCE 16B-chunk pre-permuted
// chunk_src = chunk_dst ^ (row&7); READ applies same involution.
#define BM 128
#define BK 64
__global__ __launch_bounds__(256) void gemm_nt(
    const bf16* __restrict__ A, const bf16* __restrict__ B,
    int lda, int kSteps, float* __restrict__ part, int ldc, size_t zStride) {
    __shared__ short Al[2][BM * BK];
    __shared__ short Bl[2][BM * BK];
    int tid = threadIdx.x;
    int bm = blockIdx.x * BM;
    int bn = blockIdx.y * BM;
    int z = blockIdx.z;
    int wave = tid >> 6, lane = tid & 63;
    int wm = (wave >> 1) * 64, wn = (wave & 1) * 64;
    int lr = lane & 15, lk = lane >> 4;
    int rowS = wave * 8 + (lane >> 3);               // staging row (LDS dest, linear)
    int colS = (lane & 7) * 8;                        // LDS dest col (elements)
    int colSrc = (((lane & 7) ^ ((lane >> 3) & 7))) * 8;  // swizzled GLOBAL source col

    f32x4 acc[4][4];
#pragma unroll
    for (int i = 0; i < 4; ++i)
#pragma unroll
        for (int j = 0; j < 4; ++j) acc[i][j] = (f32x4){0.f, 0.f, 0.f, 0.f};

    const bf16* gA = A + (size_t)(bm + rowS) * lda + colSrc + (size_t)z * kSteps * BK;
    const bf16* gB = B + (size_t)(bn + rowS) * lda + colSrc + (size_t)z * kSteps * BK;

    auto STAGE = [&](int buf, int kt) {
        size_t ko = (size_t)kt * BK;
#pragma unroll
        for (int it = 0; it < 4; ++it) {
            async_load16(gA + ko + (size_t)it * 32 * lda, &Al[buf][(it * 32 + rowS) * BK + colS]);
            async_load16(gB + ko + (size_t)it * 32 * lda, &Bl[buf][(it * 32 + rowS) * BK + colS]);
        }
    };
    auto COMPUTE = [&](int buf) {
#pragma unroll
        for (int ks = 0; ks < 2; ++ks) {
            bf16x8s af[4], bfr[4];
#pragma unroll
            for (int i = 0; i < 4; ++i) {
                int row = wm + i * 16 + lr;
                int ch = ((ks * 4 + lk) ^ (lr & 7)) * 8;
                af[i] = *(const bf16x8s*)&Al[buf][row * BK + ch];
            }
#pragma unroll
            for (int j = 0; j < 4; ++j) {
                int row = wn + j * 16 + lr;
                int ch = ((ks * 4 + lk) ^ (lr & 7)) * 8;
                bfr[j] = *(const bf16x8s*)&Bl[buf][row * BK + ch];
            }
#pragma unroll
            for (int i = 0; i < 4; ++i)
#pragma unroll
                for (int j = 0; j < 4; ++j)
                    acc[i][j] = __builtin_amdgcn_mfma_f32_16x16x32_bf16(af[i], bfr[j], acc[i][j], 0, 0, 0);
        }
    };

    int cur = 0;
    STAGE(0, 0);
    asm volatile("s_waitcnt vmcnt(0)" ::: "memory");
    __syncthreads();
    for (int kt = 0; kt < kSteps; ++kt) {
        if (kt + 1 < kSteps) STAGE(cur ^ 1, kt + 1);
        COMPUTE(cur);
        asm volatile("s_waitcnt vmcnt(0)" ::: "memory");
        __syncthreads();
        cur ^= 1;
    }
    float* outp = part + (size_t)z * zStride;
#pragma unroll
    for (int i = 0; i < 4; ++i) {
        int mbase = bm + wm + i * 16 + lk * 4;
#pragma unroll
        for (int j = 0; j < 4; ++j) {
            int ncol = bn + wn + j * 16 + lr;
#pragma unroll
            for (int r = 0; r < 4; ++r)
                outp[(size_t)(mbase + r) * ldc + ncol] = acc[i][j][r];
        }
    }
}

// ---------------- split-K reduce (+bias, +relu) -> bf16 or f32 ----------------
__global__ void reduceK(const float* __restrict__ part, int nsplit, size_t zStride,
                        const float* __restrict__ bias, int colMask, int relu,
                        bf16* __restrict__ outB, float* __restrict__ outF) {
    int idx = blockIdx.x * 256 + threadIdx.x;
    float v = bias ? bias[idx & colMask] : 0.f;
    for (int s = 0; s < nsplit; ++s) v += part[(size_t)s * zStride + idx];
    if (relu) v = fmaxf(v, 0.f);
    if (outB) outB[idx] = __float2bfloat16(v);
    else outF[idx] = v;
}

// ------------ softmax + box decode + direct candidate push (compact fused) ------------
__global__ __launch_bounds__(128) void decode(
    const float* __restrict__ heads,
    const float* __restrict__ bcls, const float* __restrict__ breg,
    const float* __restrict__ props, const int* __restrict__ imidx,
    float* __restrict__ boxes, u64* __restrict__ cand, int* __restrict__ cnt) {
    __shared__ float red[128];
    int n = blockIdx.x, t = threadIdx.x;
    float l = (t < NCLS) ? heads[(size_t)n * NHEAD + t] + bcls[t] : -1e30f;
    red[t] = l; __syncthreads();
    for (int s = 64; s > 0; s >>= 1) { if (t < s) red[t] = fmaxf(red[t], red[t + s]); __syncthreads(); }
    float mx = red[0]; __syncthreads();
    float e = (t < NCLS) ? expf(l - mx) : 0.f;
    red[t] = e; __syncthreads();
    for (int s = 64; s > 0; s >>= 1) { if (t < s) red[t] += red[t + s]; __syncthreads(); }
    float denom = red[0];
    if (t >= NCG) return;
    float score = e / denom;
    float px1 = props[n * 4 + 0], py1 = props[n * 4 + 1];
    float px2 = props[n * 4 + 2], py2 = props[n * 4 + 3];
    float pw = px2 - px1, ph = py2 - py1;
    float pcx = px1 + 0.5f * pw, pcy = py1 + 0.5f * ph;
    const float* r4 = heads + (size_t)n * NHEAD + 128 + t * 4;
    float dx = (r4[0] + breg[t * 4 + 0]) * 0.1f;
    float dy = (r4[1] + breg[t * 4 + 1]) * 0.1f;
    float dw = fminf((r4[2] + breg[t * 4 + 2]) * 0.2f, DWH_CLAMP_F);
    float dh = fminf((r4[3] + breg[t * 4 + 3]) * 0.2f, DWH_CLAMP_F);
    float cx = pcx + dx * pw, cy = pcy + dy * ph;
    float bw = pw * expf(dw), bh = ph * expf(dh);
    float x1 = fminf(fmaxf(cx - 0.5f * bw, 0.f), IMGSZ);
    float y1 = fminf(fmaxf(cy - 0.5f * bh, 0.f), IMGSZ);
    float x2 = fminf(fmaxf(cx + 0.5f * bw, 0.f), IMGSZ);
    float y2 = fminf(fmaxf(cy + 0.5f * bh, 0.f), IMGSZ);
    int idx = n * NCG + t;
    float* bo = boxes + (size_t)idx * 4;
    bo[0] = x1; bo[1] = y1; bo[2] = x2; bo[3] = y2;
    bool valid = (score > SCORE_THR) && ((x2 - x1) >= MIN_SIZE) && ((y2 - y1) >= MIN_SIZE);
    if (valid) {
        u64 key = ((u64)__float_as_uint(score) << 17) | (u64)(0x1FFFFu - (unsigned)idx);
        int p = atomicAdd(cnt, 1);
        if (p < CAND) cand[p] = key;
    }
}

// -------- bitonic descending sort (dynamic size) + top-1000 attribute extract, one block --------
__global__ __launch_bounds__(1024) void sort_extract(
    const u64* __restrict__ cand, const int* __restrict__ cntp,
    const float* __restrict__ boxes, const int* __restrict__ imidx,
    float* __restrict__ tb, float* __restrict__ toff,
    float* __restrict__ ts, int* __restrict__ tc, int* __restrict__ ti) {
    __shared__ u64 s[CAND];
    int t = threadIdx.x;
    int n = min(*cntp, CAND);
    if (n > 0) {
        int NS = (n <= 1024) ? 1024 : ((n <= 2048) ? 2048 : 4096);
        int E = NS >> 10;
        for (int p = 0; p < E; ++p) { int i = t + p * 1024; s[i] = (i < n) ? cand[i] : 0ull; }
        __syncthreads();
        for (int k = 2; k <= NS; k <<= 1) {
            for (int j = k >> 1; j > 0; j >>= 1) {
                for (int p = 0; p < E; ++p) {
                    int i = t + p * 1024;
                    int l = i ^ j;
                    if (l > i && l < NS) {
                        u64 a = s[i], b = s[l];
                        bool desc = ((i & k) == 0);
                        if (desc ? (a < b) : (a > b)) { s[i] = b; s[l] = a; }
                    }
                }
                __syncthreads();
            }
        }
    }
    if (t >= KNMS) return;
    u64 key = (n > 0) ? s[t] : 0ull;
    if (key == 0ull) {
        ts[t] = -1.f; tc[t] = -1; ti[t] = -1;
        for (int d = 0; d < 4; ++d) { tb[t * 4 + d] = 0.f; toff[t * 4 + d] = 0.f; }
        return;
    }
    unsigned idx = 0x1FFFFu - (unsigned)(key & 0x1FFFFull);
    float score = __uint_as_float((unsigned)(key >> 17));
    int nn = idx / NCG, c = idx - nn * NCG;
    int im = imidx[nn];
    float off = (float)(im * NCG + c) * 1000.0f;
    for (int d = 0; d < 4; ++d) {
        float v = boxes[(size_t)idx * 4 + d];
        tb[t * 4 + d] = v;
        toff[t * 4 + d] = v + off;
    }
    ts[t] = score; tc[t] = c; ti[t] = im;
}

// ------------- fused greedy NMS + parallel per-image top-100 writeout -------------
__global__ __launch_bounds__(256) void nms_write(
    const float* __restrict__ toff, const float* __restrict__ tb,
    const float* __restrict__ ts, const int* __restrict__ tc, const int* __restrict__ ti,
    float* __restrict__ out) {
    __shared__ float4 bx[KNMS];
    __shared__ int kp[KNMS];
    __shared__ int Vsh;
    __shared__ unsigned scan[256];
    int t = threadIdx.x;
    if (t == 0) Vsh = KNMS;
    __syncthreads();
    for (int s = t; s < KNMS; s += 256) {
        bx[s] = ((const float4*)toff)[s];
        bool ok = ts[s] > 0.f;
        kp[s] = ok ? 1 : 0;
        if (!ok) atomicMin(&Vsh, s);
    }
    __syncthreads();
    int V = Vsh;   // valid entries form a prefix (sorted descending)
    for (int i = 0; i < V; ++i) {
        if (kp[i]) {
            float4 bi = bx[i];
            float ai = (bi.z - bi.x) * (bi.w - bi.y);
            for (int j2 = i + 1 + t; j2 < V; j2 += 256) {
                if (!kp[j2]) continue;
                float4 bj = bx[j2];
                float xx1 = fmaxf(bi.x, bj.x), yy1 = fmaxf(bi.y, bj.y);
                float xx2 = fminf(bi.z, bj.z), yy2 = fminf(bi.w, bj.w);
                float iw = fmaxf(xx2 - xx1, 0.f), ih = fmaxf(yy2 - yy1, 0.f);
                float inter = iw * ih;
                float aj = (bj.z - bj.x) * (bj.w - bj.y);
                float iou = inter / fmaxf(ai + aj - inter, 1e-9f);
                if (iou > 0.5f) kp[j2] = 0;
            }
        }
        __syncthreads();
    }
    for (int r = t; r < 200; r += 256) {
        for (int d = 0; d < 4; ++d) out[r * 4 + d] = 0.f;
        out[800 + r] = 0.f;
        out[1000 + r] = -1.0f;
    }
    unsigned loc[4];
    unsigned mycnt = 0;
    #pragma unroll
    for (int q = 0; q < 4; ++q) {
        int s = t * 4 + q;
        unsigned f = 0;
        if (s < KNMS && kp[s] && ts[s] > 0.f) f = (ti[s] == 0) ? 1u : 0x10000u;
        loc[q] = f;
        mycnt += f;
    }
    scan[t] = mycnt;
    __syncthreads();
    for (int d = 1; d < 256; d <<= 1) {
        unsigned v = scan[t];
        unsigned add = (t >= d) ? scan[t - d] : 0u;
        __syncthreads();
        scan[t] = v + add;
        __syncthreads();
    }
    unsigned base = (t > 0) ? scan[t - 1] : 0u;
    #pragma unroll
    for (int q = 0; q < 4; ++q) {
        unsigned f = loc[q];
        if (f) {
            int im = (f >> 16) ? 1 : 0;
            unsigned rank = (im ? (base >> 16) : (base & 0xFFFFu));
            if (rank < 100) {
                int s = t * 4 + q;
                int slot = im * 100 + (int)rank;
                for (int d = 0; d < 4; ++d) out[slot * 4 + d] = tb[s * 4 + d];
                out[800 + slot] = ts[s];
                out[1000 + slot] = (float)tc[s];
            }
            base += f;
        }
    }
}

// =====================================================================
extern "C" void kernel_launch(void* const* d_in, const int* in_sizes, int n_in,
                              void* d_out, int out_size, void* d_ws, size_t ws_size,
                              hipStream_t stream) {
    (void)in_sizes; (void)n_in; (void)out_size; (void)ws_size;
    const float* props = (const float*)d_in[0];
    const int*   imidx = (const int*)d_in[1];
    const float* fm0 = (const float*)d_in[2];
    const float* fm1 = (const float*)d_in[3];
    const float* fm2 = (const float*)d_in[4];
    const float* fm3 = (const float*)d_in[5];
    const float* Wfc0 = (const float*)d_in[6];
    const float* bfc0 = (const float*)d_in[7];
    const float* Wfc1 = (const float*)d_in[8];
    const float* bfc1 = (const float*)d_in[9];
    const float* Wcls = (const float*)d_in[10];
    const float* bcls = (const float*)d_in[11];
    const float* Wreg = (const float*)d_in[12];
    const float* breg = (const float*)d_in[13];

    char* p = (char*)d_ws;
    auto alloc = [&](size_t bytes) { char* r = p; p += (bytes + 255) & ~(size_t)255; return r; };

    bf16* fmt0 = (bf16*)alloc((size_t)2 * 40000 * CH * 2);  // 41 MB; re-used as split-K scratch
    bf16* fmt1 = (bf16*)alloc((size_t)2 * 10000 * CH * 2);
    bf16* fmt2 = (bf16*)alloc((size_t)2 * 2500 * CH * 2);
    bf16* fmt3 = (bf16*)alloc((size_t)2 * 625 * CH * 2);
    bf16* Wt0 = (bf16*)alloc((size_t)CLIN * KPAD * 2);
    bf16* Wt1 = (bf16*)alloc((size_t)CLIN * CLIN * 2);
    bf16* Wth = (bf16*)alloc((size_t)NHEAD * CLIN * 2);
    bf16* x0 = (bf16*)alloc((size_t)MPAD * KPAD * 2);
    bf16* x1 = (bf16*)alloc((size_t)MPAD * CLIN * 2);
    bf16* x2 = (bf16*)alloc((size_t)MPAD * CLIN * 2);
    float* heads = (float*)alloc((size_t)MPAD * NHEAD * 4);
    float* boxes = (float*)alloc((size_t)NPROP * NCG * 4 * 4);
    u64* cand = (u64*)alloc((size_t)CAND * 8);
    float* tb = (float*)alloc(KNMS * 4 * 4);
    float* toff = (float*)alloc(KNMS * 4 * 4);
    float* ts = (float*)alloc(KNMS * 4);
    int* tc = (int*)alloc(KNMS * 4);
    int* ti = (int*)alloc(KNMS * 4);
    int* cnt = (int*)alloc(256);
    float* Cpart = (float*)fmt0;

    dim3 b328(32, 8, 1);
    fm_transpose_all<<<dim3(1662, 8, 2), b328, 0, stream>>>(fm0, fm1, fm2, fm3,
                                                            fmt0, fmt1, fmt2, fmt3);
    wfc0_transpose<<<dim3(50, 8, 32), b328, 0, stream>>>(Wfc0, Wt0);
    w_transpose<<<dim3(32, 32, 1), b328, 0, stream>>>(Wfc1, Wt1, CLIN);
    whead_transpose<<<dim3(32, 16, 1), b328, 0, stream>>>(Wcls, Wreg, Wth);

    roi_align<<<dim3(MPAD), 256, 0, stream>>>(props, imidx, fmt0, fmt1, fmt2, fmt3, x0);

    gemm_nt<<<dim3(8, 8, 8), 256, 0, stream>>>(x0, Wt0, KPAD, 25, Cpart, CLIN, (size_t)MPAD * CLIN);
    reduceK<<<dim3(MPAD * CLIN / 256), 256, 0, stream>>>(Cpart, 8, (size_t)MPAD * CLIN,
        bfc0, CLIN - 1, 1, x1, nullptr);
    gemm_nt<<<dim3(8, 8, 4), 256, 0, stream>>>(x1, Wt1, CLIN, 4, Cpart, CLIN, (size_t)MPAD * CLIN);
    reduceK<<<dim3(MPAD * CLIN / 256), 256, 0, stream>>>(Cpart, 4, (size_t)MPAD * CLIN,
        bfc1, CLIN - 1, 1, x2, nullptr);
    gemm_nt<<<dim3(8, 4, 8), 256, 0, stream>>>(x2, Wth, CLIN, 2, Cpart, NHEAD, (size_t)MPAD * NHEAD);
    reduceK<<<dim3(MPAD * NHEAD / 256), 256, 0, stream>>>(Cpart, 8, (size_t)MPAD * NHEAD,
        nullptr, 0, 0, nullptr, heads);

    hipMemsetAsync(cnt, 0, 4, stream);
    decode<<<dim3(NPROP), 128, 0, stream>>>(heads, bcls, breg, props, imidx, boxes, cand, cnt);
    sort_extract<<<dim3(1), 1024, 0, stream>>>(cand, cnt, boxes, imidx, tb, toff, ts, tc, ti);
    nms_write<<<dim3(1), 256, 0, stream>>>(toff, tb, ts, tc, ti, (float*)d_out);
}

// Round 6
// 196.447 us; speedup vs baseline: 3.0074x; 1.0253x over previous
//
#include <hip/hip_runtime.h>
#include <hip/hip_bf16.h>
#include <stdint.h>
#include <stddef.h>

typedef __hip_bfloat16 bf16;
typedef short bf16x8s __attribute__((ext_vector_type(8)));
typedef float f32x4 __attribute__((ext_vector_type(4)));
typedef unsigned long long u64;

#define NPROP 1000
#define MPAD  1024
#define NCG   80
#define NCLS  81
#define CH    256
#define KDIM  12544
#define KPAD  12800     // 50 cells * 256
#define CLIN  1024
#define NHEAD 512       // packed heads: [0,81)=cls, [128,448)=reg
#define IMGSZ 800.0f
#define SCORE_THR 0.05f
#define MIN_SIZE 0.01f
#define KNMS 1000
#define CAND 4096
#define DWH_CLAMP_F 4.135166556742356f

__device__ __forceinline__ void async_load16(const void* g, void* l) {
    __builtin_amdgcn_global_load_lds(
        (const __attribute__((address_space(1))) void*)g,
        (__attribute__((address_space(3))) void*)l, 16, 0, 0);
}

__device__ __forceinline__ unsigned short bfbits(float x) {
    return __builtin_bit_cast(unsigned short, __float2bfloat16(x));
}

// ---- 64(c) x 64(s) transpose tile: f32 [c][s] -> bf16 [s][c], vectorized both sides ----
// src: element (c_local, s) at src + c_local*cstride + s   (s in [sBase, sBase+64), guard sMax)
// dst: element (s, c_local) at dst + s*ldo + c_local
__device__ __forceinline__ void tile64(const float* __restrict__ src, size_t cstride,
                                       int sBase, int sMax,
                                       bf16* __restrict__ dst, size_t ldo) {
    __shared__ unsigned short tile[64][66];   // 66 u16 row = 33 words (odd) -> spread banks
    int tid = threadIdx.x;
    int s4 = (tid & 15) * 4;           // local s of this thread's float4
    int sg = sBase + s4;
#pragma unroll
    for (int g = 0; g < 4; ++g) {
        int cl = g * 16 + (tid >> 4);
        const float* p = src + (size_t)cl * cstride;
        float4 v = make_float4(0.f, 0.f, 0.f, 0.f);
        if (sg + 3 < sMax) {
            v = *(const float4*)(p + sg);
        } else {
            if (sg + 0 < sMax) v.x = p[sg + 0];
            if (sg + 1 < sMax) v.y = p[sg + 1];
            if (sg + 2 < sMax) v.z = p[sg + 2];
            if (sg + 3 < sMax) v.w = p[sg + 3];
        }
        unsigned lo = (unsigned)bfbits(v.x) | ((unsigned)bfbits(v.y) << 16);
        unsigned hi = (unsigned)bfbits(v.z) | ((unsigned)bfbits(v.w) << 16);
        unsigned* q = (unsigned*)&tile[cl][s4];
        q[0] = lo; q[1] = hi;
    }
    __syncthreads();
    int sl = tid >> 2;                 // local s, 0..63
    int cg16 = (tid & 3) * 16;         // 16-channel chunk
    if (sBase + sl < sMax) {
        unsigned short r[16];
#pragma unroll
        for (int i = 0; i < 16; ++i) r[i] = tile[cg16 + i][sl];
        uint4 o0, o1;
        o0.x = (unsigned)r[0]  | ((unsigned)r[1]  << 16);
        o0.y = (unsigned)r[2]  | ((unsigned)r[3]  << 16);
        o0.z = (unsigned)r[4]  | ((unsigned)r[5]  << 16);
        o0.w = (unsigned)r[6]  | ((unsigned)r[7]  << 16);
        o1.x = (unsigned)r[8]  | ((unsigned)r[9]  << 16);
        o1.y = (unsigned)r[10] | ((unsigned)r[11] << 16);
        o1.z = (unsigned)r[12] | ((unsigned)r[13] << 16);
        o1.w = (unsigned)r[14] | ((unsigned)r[15] << 16);
        uint4* dp = (uint4*)(dst + (size_t)(sBase + sl) * ldo + cg16);
        dp[0] = o0; dp[1] = o1;
    }
}

// ---------------- feature map transpose, all 4 levels: NCHW f32 -> NHWC bf16 ----------------
__global__ __launch_bounds__(256) void fm_t64(
    const float* __restrict__ f0, const float* __restrict__ f1,
    const float* __restrict__ f2, const float* __restrict__ f3,
    bf16* __restrict__ o0, bf16* __restrict__ o1,
    bf16* __restrict__ o2, bf16* __restrict__ o3) {
    int tx = blockIdx.x;               // 832 s-tiles across levels
    int cg = blockIdx.y;               // 4 channel groups of 64
    int b = blockIdx.z;                // 2 images
    const float* fm; bf16* ft; int S;
    if (tx < 625)      { fm = f0; ft = o0; S = 40000; }
    else if (tx < 782) { fm = f1; ft = o1; S = 10000; tx -= 625; }
    else if (tx < 822) { fm = f2; ft = o2; S = 2500;  tx -= 782; }
    else               { fm = f3; ft = o3; S = 625;   tx -= 822; }
    const float* src = fm + ((size_t)b * CH + cg * 64) * S;
    bf16* dst = ft + (size_t)b * S * CH + cg * 64;
    tile64(src, (size_t)S, tx * 64, S, dst, CH);
}

// --------- W_fc0 (12544x1024) -> Wt0 (1024 x KPAD), k' = cell*256 + c ----------
__global__ __launch_bounds__(256) void wfc0_t64(const float* __restrict__ W, bf16* __restrict__ Wt) {
    int tn = blockIdx.x;               // 16 n-tiles
    int cg = blockIdx.y;               // 4 channel groups
    int cell = blockIdx.z;             // 49 cells
    const float* src = W + (size_t)cell * CLIN + (size_t)(cg * 64) * 50176;  // 50176 = 49*1024
    bf16* dst = Wt + cell * 256 + cg * 64;
    tile64(src, 50176, tn * 64, 1024, dst, KPAD);
}

// --------- zero the pad cell (49) of Wt0 ----------
__global__ void wt0_zero(bf16* __restrict__ Wt) {
    int i = blockIdx.x * 256 + threadIdx.x;    // 1024 * 128 u32
    int n = i >> 7, c2 = i & 127;
    ((unsigned*)Wt)[(size_t)n * (KPAD / 2) + 49 * 128 + c2] = 0u;
}

// --------- W (1024 x ncols) -> Wt (npad x 1024) bf16 ----------
__global__ void w_transpose(const float* __restrict__ W, bf16* __restrict__ Wt, int ncols) {
    __shared__ float tile[32][33];
    int kBase = blockIdx.x * 32;
    int nBase = blockIdx.y * 32;
    int tx = threadIdx.x, ty = threadIdx.y;
#pragma unroll
    for (int i = 0; i < 4; ++i) {
        int k = kBase + ty + i * 8;
        int n = nBase + tx;
        float v = 0.f;
        if (n < ncols) v = W[(size_t)k * ncols + n];
        tile[ty + i * 8][tx] = v;
    }
    __syncthreads();
#pragma unroll
    for (int i = 0; i < 4; ++i) {
        int n = nBase + ty + i * 8;
        Wt[(size_t)n * CLIN + kBase + tx] = __float2bfloat16(tile[tx][ty + i * 8]);
    }
}

// --------- packed head weights: Wth[j][k], j<81 = Wcls col j, 128<=j<448 = Wreg col j-128 ----
__global__ void whead_transpose(const float* __restrict__ Wc, const float* __restrict__ Wr,
                                bf16* __restrict__ Wt) {
    __shared__ float tile[32][33];
    int kBase = blockIdx.x * 32;
    int jBase = blockIdx.y * 32;
    int tx = threadIdx.x, ty = threadIdx.y;
#pragma unroll
    for (int i = 0; i < 4; ++i) {
        int k = kBase + ty + i * 8;
        int j = jBase + tx;
        float v = 0.f;
        if (j < NCLS) v = Wc[(size_t)k * NCLS + j];
        else if (j >= 128 && j < 448) v = Wr[(size_t)k * (NCG * 4) + (j - 128)];
        tile[ty + i * 8][tx] = v;
    }
    __syncthreads();
#pragma unroll
    for (int i = 0; i < 4; ++i) {
        int j = jBase + ty + i * 8;
        Wt[(size_t)j * CLIN + kBase + tx] = __float2bfloat16(tile[tx][ty + i * 8]);
    }
}

// ------- RoI align: block = proposal; thread = (cell-half, 2-channel group); u32 loads -------
__global__ __launch_bounds__(256) void roi_align(
    const float* __restrict__ props, const int* __restrict__ imidx,
    const bf16* __restrict__ f0, const bf16* __restrict__ f1,
    const bf16* __restrict__ f2, const bf16* __restrict__ f3,
    bf16* __restrict__ x0) {
    int n = blockIdx.x;
    int t = threadIdx.x;
    unsigned* outp = (unsigned*)(x0 + (size_t)n * KPAD);
    if (n >= NPROP) {   // zero pad rows: 6400 u32 per row
        for (int i = t; i < KPAD / 2; i += 256) outp[i] = 0u;
        return;
    }
    __shared__ int4  soff[196];   // u32-unit offsets of 4 corners
    __shared__ float4 swt[196];   // 4 corner weights (incl. 0.25 avg factor)
    float px1 = props[n * 4 + 0], py1 = props[n * 4 + 1];
    float px2 = props[n * 4 + 2], py2 = props[n * 4 + 3];
    float w = px2 - px1, h = py2 - py1;
    float lvlf = floorf(4.0f + log2f(sqrtf(fmaxf(w * h, 1e-6f)) / 224.0f));
    int lvl = (int)fminf(fmaxf(lvlf, 2.0f), 5.0f) - 2;
    const bf16* fmt; int H, Wd; float inv;
    if (lvl == 0)      { fmt = f0; H = 200; Wd = 200; inv = 0.25f; }
    else if (lvl == 1) { fmt = f1; H = 100; Wd = 100; inv = 0.125f; }
    else if (lvl == 2) { fmt = f2; H = 50;  Wd = 50;  inv = 0.0625f; }
    else               { fmt = f3; H = 25;  Wd = 25;  inv = 0.03125f; }
    const unsigned* basep = (const unsigned*)(fmt + (size_t)imidx[n] * H * Wd * CH);
    if (t < 196) {
        int py = t / 14, px = t - py * 14;
        float x1s = px1 * inv, y1s = py1 * inv;
        float dxs = w * inv, dys = h * inv;
        float fx = ((float)px + 0.5f) * (1.0f / 14.0f);
        float fy = ((float)py + 0.5f) * (1.0f / 14.0f);
        float gx = fminf(fmaxf(x1s + fx * dxs, 0.f), (float)(Wd - 1));
        float gy = fminf(fmaxf(y1s + fy * dys, 0.f), (float)(H - 1));
        float x0f = floorf(gx), y0f = floorf(gy);
        int x0i = (int)x0f, y0i = (int)y0f;
        int x1i = min(x0i + 1, Wd - 1), y1i = min(y0i + 1, H - 1);
        float lx = gx - x0f, ly = gy - y0f;
        int4 so;
        so.x = (y0i * Wd + x0i) * (CH / 2);
        so.y = (y0i * Wd + x1i) * (CH / 2);
        so.z = (y1i * Wd + x0i) * (CH / 2);
        so.w = (y1i * Wd + x1i) * (CH / 2);
        soff[t] = so;
        float4 wt;
        wt.x = 0.25f * (1.f - ly) * (1.f - lx);
        wt.y = 0.25f * (1.f - ly) * lx;
        wt.z = 0.25f * ly * (1.f - lx);
        wt.w = 0.25f * ly * lx;
        swt[t] = wt;
    }
    __syncthreads();
    int half = t >> 7;           // 0: cells 0..24, 1: cells 25..48
    int tc = t & 127;            // u32 channel group (2 bf16 channels)
    int c0 = half ? 25 : 0;
    int cN = half ? 24 : 25;
    for (int k = 0; k < cN; ++k) {
        int cell = c0 + k;
        int ci = cell / 7, cj = cell - ci * 7;
        float accL = 0.f, accH = 0.f;
#pragma unroll
        for (int sy = 0; sy < 2; ++sy) {
#pragma unroll
            for (int sx = 0; sx < 2; ++sx) {
                int p = (ci * 2 + sy) * 14 + (cj * 2 + sx);
                int4 so = soff[p];
                float4 wt = swt[p];
                unsigned u;
                u = basep[so.x + tc];
                accL += wt.x * __uint_as_float(u << 16);
                accH += wt.x * __uint_as_float(u & 0xFFFF0000u);
                u = basep[so.y + tc];
                accL += wt.y * __uint_as_float(u << 16);
                accH += wt.y * __uint_as_float(u & 0xFFFF0000u);
                u = basep[so.z + tc];
                accL += wt.z * __uint_as_float(u << 16);
                accH += wt.z * __uint_as_float(u & 0xFFFF0000u);
                u = basep[so.w + tc];
                accL += wt.w * __uint_as_float(u << 16);
                accH += wt.w * __uint_as_float(u & 0xFFFF0000u);
            }
        }
        unsigned lo = (unsigned)bfbits(accL);
        unsigned hi = (unsigned)bfbits(accH);
        outp[cell * 128 + tc] = lo | (hi << 16);
    }
    if (half == 0) outp[49 * 128 + tc] = 0u;   // zero pad cell
}

// -------- bf16 MFMA NT-GEMM: gload_lds + dbuf + 2-phase prefetch + XOR-swizzled LDS ---------
#define BM 128
#define BK 64
__global__ __launch_bounds__(256) void gemm_nt(
    const bf16* __restrict__ A, const bf16* __restrict__ B,
    int lda, int kSteps, float* __restrict__ part, int ldc, size_t zStride) {
    __shared__ short Al[2][BM * BK];
    __shared__ short Bl[2][BM * BK];
    int tid = threadIdx.x;
    int bm = blockIdx.x * BM;
    int bn = blockIdx.y * BM;
    int z = blockIdx.z;
    int wave = tid >> 6, lane = tid & 63;
    int wm = (wave >> 1) * 64, wn = (wave & 1) * 64;
    int lr = lane & 15, lk = lane >> 4;
    int rowS = wave * 8 + (lane >> 3);               // staging row (LDS dest, linear)
    int colS = (lane & 7) * 8;                        // LDS dest col (elements)
    int colSrc = (((lane & 7) ^ ((lane >> 3) & 7))) * 8;  // swizzled GLOBAL source col

    f32x4 acc[4][4];
#pragma unroll
    for (int i = 0; i < 4; ++i)
#pragma unroll
        for (int j = 0; j < 4; ++j) acc[i][j] = (f32x4){0.f, 0.f, 0.f, 0.f};

    const bf16* gA = A + (size_t)(bm + rowS) * lda + colSrc + (size_t)z * kSteps * BK;
    const bf16* gB = B + (size_t)(bn + rowS) * lda + colSrc + (size_t)z * kSteps * BK;

    auto STAGE = [&](int buf, int kt) {
        size_t ko = (size_t)kt * BK;
#pragma unroll
        for (int it = 0; it < 4; ++it) {
            async_load16(gA + ko + (size_t)it * 32 * lda, &Al[buf][(it * 32 + rowS) * BK + colS]);
            async_load16(gB + ko + (size_t)it * 32 * lda, &Bl[buf][(it * 32 + rowS) * BK + colS]);
        }
    };
    auto COMPUTE = [&](int buf) {
#pragma unroll
        for (int ks = 0; ks < 2; ++ks) {
            bf16x8s af[4], bfr[4];
#pragma unroll
            for (int i = 0; i < 4; ++i) {
                int row = wm + i * 16 + lr;
                int ch = ((ks * 4 + lk) ^ (lr & 7)) * 8;
                af[i] = *(const bf16x8s*)&Al[buf][row * BK + ch];
            }
#pragma unroll
            for (int j = 0; j < 4; ++j) {
                int row = wn + j * 16 + lr;
                int ch = ((ks * 4 + lk) ^ (lr & 7)) * 8;
                bfr[j] = *(const bf16x8s*)&Bl[buf][row * BK + ch];
            }
#pragma unroll
            for (int i = 0; i < 4; ++i)
#pragma unroll
                for (int j = 0; j < 4; ++j)
                    acc[i][j] = __builtin_amdgcn_mfma_f32_16x16x32_bf16(af[i], bfr[j], acc[i][j], 0, 0, 0);
        }
    };

    int cur = 0;
    STAGE(0, 0);
    asm volatile("s_waitcnt vmcnt(0)" ::: "memory");
    __syncthreads();
    for (int kt = 0; kt < kSteps; ++kt) {
        if (kt + 1 < kSteps) STAGE(cur ^ 1, kt + 1);
        COMPUTE(cur);
        asm volatile("s_waitcnt vmcnt(0)" ::: "memory");
        __syncthreads();
        cur ^= 1;
    }
    float* outp = part + (size_t)z * zStride;
#pragma unroll
    for (int i = 0; i < 4; ++i) {
        int mbase = bm + wm + i * 16 + lk * 4;
#pragma unroll
        for (int j = 0; j < 4; ++j) {
            int ncol = bn + wn + j * 16 + lr;
#pragma unroll
            for (int r = 0; r < 4; ++r)
                outp[(size_t)(mbase + r) * ldc + ncol] = acc[i][j][r];
        }
    }
}

// ---------------- split-K reduce (+bias, +relu) -> bf16 or f32 ----------------
__global__ void reduceK(const float* __restrict__ part, int nsplit, size_t zStride,
                        const float* __restrict__ bias, int colMask, int relu,
                        bf16* __restrict__ outB, float* __restrict__ outF) {
    int idx = blockIdx.x * 256 + threadIdx.x;
    float v = bias ? bias[idx & colMask] : 0.f;
    for (int s = 0; s < nsplit; ++s) v += part[(size_t)s * zStride + idx];
    if (relu) v = fmaxf(v, 0.f);
    if (outB) outB[idx] = __float2bfloat16(v);
    else outF[idx] = v;
}

// ------------ softmax + box decode + direct candidate push (compact fused) ------------
__global__ __launch_bounds__(128) void decode(
    const float* __restrict__ heads,
    const float* __restrict__ bcls, const float* __restrict__ breg,
    const float* __restrict__ props, const int* __restrict__ imidx,
    float* __restrict__ boxes, u64* __restrict__ cand, int* __restrict__ cnt) {
    __shared__ float red[128];
    int n = blockIdx.x, t = threadIdx.x;
    float l = (t < NCLS) ? heads[(size_t)n * NHEAD + t] + bcls[t] : -1e30f;
    red[t] = l; __syncthreads();
    for (int s = 64; s > 0; s >>= 1) { if (t < s) red[t] = fmaxf(red[t], red[t + s]); __syncthreads(); }
    float mx = red[0]; __syncthreads();
    float e = (t < NCLS) ? expf(l - mx) : 0.f;
    red[t] = e; __syncthreads();
    for (int s = 64; s > 0; s >>= 1) { if (t < s) red[t] += red[t + s]; __syncthreads(); }
    float denom = red[0];
    if (t >= NCG) return;
    float score = e / denom;
    float px1 = props[n * 4 + 0], py1 = props[n * 4 + 1];
    float px2 = props[n * 4 + 2], py2 = props[n * 4 + 3];
    float pw = px2 - px1, ph = py2 - py1;
    float pcx = px1 + 0.5f * pw, pcy = py1 + 0.5f * ph;
    const float* r4 = heads + (size_t)n * NHEAD + 128 + t * 4;
    float dx = (r4[0] + breg[t * 4 + 0]) * 0.1f;
    float dy = (r4[1] + breg[t * 4 + 1]) * 0.1f;
    float dw = fminf((r4[2] + breg[t * 4 + 2]) * 0.2f, DWH_CLAMP_F);
    float dh = fminf((r4[3] + breg[t * 4 + 3]) * 0.2f, DWH_CLAMP_F);
    float cx = pcx + dx * pw, cy = pcy + dy * ph;
    float bw = pw * expf(dw), bh = ph * expf(dh);
    float x1 = fminf(fmaxf(cx - 0.5f * bw, 0.f), IMGSZ);
    float y1 = fminf(fmaxf(cy - 0.5f * bh, 0.f), IMGSZ);
    float x2 = fminf(fmaxf(cx + 0.5f * bw, 0.f), IMGSZ);
    float y2 = fminf(fmaxf(cy + 0.5f * bh, 0.f), IMGSZ);
    int idx = n * NCG + t;
    float* bo = boxes + (size_t)idx * 4;
    bo[0] = x1; bo[1] = y1; bo[2] = x2; bo[3] = y2;
    bool valid = (score > SCORE_THR) && ((x2 - x1) >= MIN_SIZE) && ((y2 - y1) >= MIN_SIZE);
    if (valid) {
        u64 key = ((u64)__float_as_uint(score) << 17) | (u64)(0x1FFFFu - (unsigned)idx);
        int p = atomicAdd(cnt, 1);
        if (p < CAND) cand[p] = key;
    }
}

// -------- bitonic descending sort (dynamic size) + top-1000 attribute extract, one block --------
__global__ __launch_bounds__(1024) void sort_extract(
    const u64* __restrict__ cand, const int* __restrict__ cntp,
    const float* __restrict__ boxes, const int* __restrict__ imidx,
    float* __restrict__ tb, float* __restrict__ toff,
    float* __restrict__ ts, int* __restrict__ tc, int* __restrict__ ti) {
    __shared__ u64 s[CAND];
    int t = threadIdx.x;
    int n = min(*cntp, CAND);
    if (n > 0) {
        int NS = (n <= 1024) ? 1024 : ((n <= 2048) ? 2048 : 4096);
        int E = NS >> 10;
        for (int p = 0; p < E; ++p) { int i = t + p * 1024; s[i] = (i < n) ? cand[i] : 0ull; }
        __syncthreads();
        for (int k = 2; k <= NS; k <<= 1) {
            for (int j = k >> 1; j > 0; j >>= 1) {
                for (int p = 0; p < E; ++p) {
                    int i = t + p * 1024;
                    int l = i ^ j;
                    if (l > i && l < NS) {
                        u64 a = s[i], b = s[l];
                        bool desc = ((i & k) == 0);
                        if (desc ? (a < b) : (a > b)) { s[i] = b; s[l] = a; }
                    }
                }
                __syncthreads();
            }
        }
    }
    if (t >= KNMS) return;
    u64 key = (n > 0) ? s[t] : 0ull;
    if (key == 0ull) {
        ts[t] = -1.f; tc[t] = -1; ti[t] = -1;
        for (int d = 0; d < 4; ++d) { tb[t * 4 + d] = 0.f; toff[t * 4 + d] = 0.f; }
        return;
    }
    unsigned idx = 0x1FFFFu - (unsigned)(key & 0x1FFFFull);
    float score = __uint_as_float((unsigned)(key >> 17));
    int nn = idx / NCG, c = idx - nn * NCG;
    int im = imidx[nn];
    float off = (float)(im * NCG + c) * 1000.0f;
    for (int d = 0; d < 4; ++d) {
        float v = boxes[(size_t)idx * 4 + d];
        tb[t * 4 + d] = v;
        toff[t * 4 + d] = v + off;
    }
    ts[t] = score; tc[t] = c; ti[t] = im;
}

// ------------- fused greedy NMS + parallel per-image top-100 writeout -------------
__global__ __launch_bounds__(256) void nms_write(
    const float* __restrict__ toff, const float* __restrict__ tb,
    const float* __restrict__ ts, const int* __restrict__ tc, const int* __restrict__ ti,
    float* __restrict__ out) {
    __shared__ float4 bx[KNMS];
    __shared__ int kp[KNMS];
    __shared__ int Vsh;
    __shared__ unsigned scan[256];
    int t = threadIdx.x;
    if (t == 0) Vsh = KNMS;
    __syncthreads();
    for (int s = t; s < KNMS; s += 256) {
        bx[s] = ((const float4*)toff)[s];
        bool ok = ts[s] > 0.f;
        kp[s] = ok ? 1 : 0;
        if (!ok) atomicMin(&Vsh, s);
    }
    __syncthreads();
    int V = Vsh;   // valid entries form a prefix (sorted descending)
    for (int i = 0; i < V; ++i) {
        if (kp[i]) {
            float4 bi = bx[i];
            float ai = (bi.z - bi.x) * (bi.w - bi.y);
            for (int j2 = i + 1 + t; j2 < V; j2 += 256) {
                if (!kp[j2]) continue;
                float4 bj = bx[j2];
                float xx1 = fmaxf(bi.x, bj.x), yy1 = fmaxf(bi.y, bj.y);
                float xx2 = fminf(bi.z, bj.z), yy2 = fminf(bi.w, bj.w);
                float iw = fmaxf(xx2 - xx1, 0.f), ih = fmaxf(yy2 - yy1, 0.f);
                float inter = iw * ih;
                float aj = (bj.z - bj.x) * (bj.w - bj.y);
                float iou = inter / fmaxf(ai + aj - inter, 1e-9f);
                if (iou > 0.5f) kp[j2] = 0;
            }
        }
        __syncthreads();
    }
    for (int r = t; r < 200; r += 256) {
        for (int d = 0; d < 4; ++d) out[r * 4 + d] = 0.f;
        out[800 + r] = 0.f;
        out[1000 + r] = -1.0f;
    }
    unsigned loc[4];
    unsigned mycnt = 0;
    #pragma unroll
    for (int q = 0; q < 4; ++q) {
        int s = t * 4 + q;
        unsigned f = 0;
        if (s < KNMS && kp[s] && ts[s] > 0.f) f = (ti[s] == 0) ? 1u : 0x10000u;
        loc[q] = f;
        mycnt += f;
    }
    scan[t] = mycnt;
    __syncthreads();
    for (int d = 1; d < 256; d <<= 1) {
        unsigned v = scan[t];
        unsigned add = (t >= d) ? scan[t - d] : 0u;
        __syncthreads();
        scan[t] = v + add;
        __syncthreads();
    }
    unsigned base = (t > 0) ? scan[t - 1] : 0u;
    #pragma unroll
    for (int q = 0; q < 4; ++q) {
        unsigned f = loc[q];
        if (f) {
            int im = (f >> 16) ? 1 : 0;
            unsigned rank = (im ? (base >> 16) : (base & 0xFFFFu));
            if (rank < 100) {
                int s = t * 4 + q;
                int slot = im * 100 + (int)rank;
                for (int d = 0; d < 4; ++d) out[slot * 4 + d] = tb[s * 4 + d];
                out[800 + slot] = ts[s];
                out[1000 + slot] = (float)tc[s];
            }
            base += f;
        }
    }
}

// =====================================================================
extern "C" void kernel_launch(void* const* d_in, const int* in_sizes, int n_in,
                              void* d_out, int out_size, void* d_ws, size_t ws_size,
                              hipStream_t stream) {
    (void)in_sizes; (void)n_in; (void)out_size; (void)ws_size;
    const float* props = (const float*)d_in[0];
    const int*   imidx = (const int*)d_in[1];
    const float* fm0 = (const float*)d_in[2];
    const float* fm1 = (const float*)d_in[3];
    const float* fm2 = (const float*)d_in[4];
    const float* fm3 = (const float*)d_in[5];
    const float* Wfc0 = (const float*)d_in[6];
    const float* bfc0 = (const float*)d_in[7];
    const float* Wfc1 = (const float*)d_in[8];
    const float* bfc1 = (const float*)d_in[9];
    const float* Wcls = (const float*)d_in[10];
    const float* bcls = (const float*)d_in[11];
    const float* Wreg = (const float*)d_in[12];
    const float* breg = (const float*)d_in[13];

    char* p = (char*)d_ws;
    auto alloc = [&](size_t bytes) { char* r = p; p += (bytes + 255) & ~(size_t)255; return r; };

    bf16* fmt0 = (bf16*)alloc((size_t)2 * 40000 * CH * 2);  // 41 MB; re-used as split-K scratch
    bf16* fmt1 = (bf16*)alloc((size_t)2 * 10000 * CH * 2);
    bf16* fmt2 = (bf16*)alloc((size_t)2 * 2500 * CH * 2);
    bf16* fmt3 = (bf16*)alloc((size_t)2 * 625 * CH * 2);
    bf16* Wt0 = (bf16*)alloc((size_t)CLIN * KPAD * 2);
    bf16* Wt1 = (bf16*)alloc((size_t)CLIN * CLIN * 2);
    bf16* Wth = (bf16*)alloc((size_t)NHEAD * CLIN * 2);
    bf16* x0 = (bf16*)alloc((size_t)MPAD * KPAD * 2);
    bf16* x1 = (bf16*)alloc((size_t)MPAD * CLIN * 2);
    bf16* x2 = (bf16*)alloc((size_t)MPAD * CLIN * 2);
    float* heads = (float*)alloc((size_t)MPAD * NHEAD * 4);
    float* boxes = (float*)alloc((size_t)NPROP * NCG * 4 * 4);
    u64* cand = (u64*)alloc((size_t)CAND * 8);
    float* tb = (float*)alloc(KNMS * 4 * 4);
    float* toff = (float*)alloc(KNMS * 4 * 4);
    float* ts = (float*)alloc(KNMS * 4);
    int* tc = (int*)alloc(KNMS * 4);
    int* ti = (int*)alloc(KNMS * 4);
    int* cnt = (int*)alloc(256);
    float* Cpart = (float*)fmt0;

    fm_t64<<<dim3(832, 4, 2), 256, 0, stream>>>(fm0, fm1, fm2, fm3, fmt0, fmt1, fmt2, fmt3);
    wfc0_t64<<<dim3(16, 4, 49), 256, 0, stream>>>(Wfc0, Wt0);
    wt0_zero<<<dim3(512), 256, 0, stream>>>(Wt0);
    dim3 b328(32, 8, 1);
    w_transpose<<<dim3(32, 32, 1), b328, 0, stream>>>(Wfc1, Wt1, CLIN);
    whead_transpose<<<dim3(32, 16, 1), b328, 0, stream>>>(Wcls, Wreg, Wth);

    roi_align<<<dim3(MPAD), 256, 0, stream>>>(props, imidx, fmt0, fmt1, fmt2, fmt3, x0);

    gemm_nt<<<dim3(8, 8, 8), 256, 0, stream>>>(x0, Wt0, KPAD, 25, Cpart, CLIN, (size_t)MPAD * CLIN);
    reduceK<<<dim3(MPAD * CLIN / 256), 256, 0, stream>>>(Cpart, 8, (size_t)MPAD * CLIN,
        bfc0, CLIN - 1, 1, x1, nullptr);
    gemm_nt<<<dim3(8, 8, 4), 256, 0, stream>>>(x1, Wt1, CLIN, 4, Cpart, CLIN, (size_t)MPAD * CLIN);
    reduceK<<<dim3(MPAD * CLIN / 256), 256, 0, stream>>>(Cpart, 4, (size_t)MPAD * CLIN,
        bfc1, CLIN - 1, 1, x2, nullptr);
    gemm_nt<<<dim3(8, 4, 8), 256, 0, stream>>>(x2, Wth, CLIN, 2, Cpart, NHEAD, (size_t)MPAD * NHEAD);
    reduceK<<<dim3(MPAD * NHEAD / 256), 256, 0, stream>>>(Cpart, 8, (size_t)MPAD * NHEAD,
        nullptr, 0, 0, nullptr, heads);

    hipMemsetAsync(cnt, 0, 4, stream);
    decode<<<dim3(NPROP), 128, 0, stream>>>(heads, bcls, breg, props, imidx, boxes, cand, cnt);
    sort_extract<<<dim3(1), 1024, 0, stream>>>(cand, cnt, boxes, imidx, tb, toff, ts, tc, ti);
    nms_write<<<dim3(1), 256, 0, stream>>>(toff, tb, ts, tc, ti, (float*)d_out);
}